// Round 4
// baseline (751.945 us; speedup 1.0000x reference)
//
#include <hip/hip_runtime.h>
#include <cstdint>
#include <cstddef>

// Problem constants: N=4, C=D=256, H=W=64, L=4096
#define NB 4
#define CH 256
#define LL 4096

typedef unsigned short u16;
typedef unsigned int u32;
typedef __attribute__((ext_vector_type(8))) short bf16x8;
typedef __attribute__((ext_vector_type(4))) float f32x4;

__device__ __forceinline__ float blo(u32 x) { return __uint_as_float(x << 16); }
__device__ __forceinline__ float bhi(u32 x) { return __uint_as_float(x & 0xffff0000u); }
__device__ __forceinline__ float b2f(u16 h) { return __uint_as_float(((u32)h) << 16); }
__device__ __forceinline__ u16 f2b(float f) {
    u32 u = __float_as_uint(f);
    u32 r = (u + 0x7fffu + ((u >> 16) & 1u)) >> 16;  // RNE
    return (u16)r;
}
__device__ __forceinline__ u32 pack2(float a, float b) {
    return (u32)f2b(a) | ((u32)f2b(b) << 16);
}

// ---------------------------------------------------------------------------
// Kernel 0: zero BN stats accumulators (512 floats)
// ---------------------------------------------------------------------------
__global__ void zero_stats(float* stats) { stats[threadIdx.x] = 0.0f; }

// ---------------------------------------------------------------------------
// Kernel 1: projections. out[d,l] = sum_c W[d,c] * x[n,c,l]
// grid (L/64, D/64, 12) where z = mat*4 + n ; mat 0=q, 1=k, 2=v
// q,k stored (N,L,D) bf16 ; vT stored (N,D,L) bf16  (MFMA fragment layouts)
// ---------------------------------------------------------------------------
__global__ __launch_bounds__(256) void proj_kernel(
    const float* __restrict__ x, const float* __restrict__ Wq,
    const float* __restrict__ Wk, const float* __restrict__ Wv,
    u16* __restrict__ q, u16* __restrict__ k, u16* __restrict__ vT) {
    const int n = blockIdx.z & 3;
    const int mat = blockIdx.z >> 2;
    const float* W = (mat == 0) ? Wq : ((mat == 1) ? Wk : Wv);
    const int l0 = blockIdx.x * 64;
    const int d0 = blockIdx.y * 64;
    const float* X = x + (size_t)n * CH * LL;

    __shared__ float Ws[16][68];
    __shared__ float Xs[16][68];

    const int tid = threadIdx.x;
    const int tx = tid & 15, ty = tid >> 4;

    float acc[4][4];
#pragma unroll
    for (int i = 0; i < 4; ++i)
#pragma unroll
        for (int j = 0; j < 4; ++j) acc[i][j] = 0.0f;

    for (int kt = 0; kt < 16; ++kt) {
        const int c0 = kt * 16;
#pragma unroll
        for (int i = 0; i < 4; ++i) {
            int e = tid + 256 * i;
            int cc = e & 15, dd = e >> 4;
            Ws[cc][dd] = W[(size_t)(d0 + dd) * CH + c0 + cc];
        }
#pragma unroll
        for (int i = 0; i < 4; ++i) {
            int e = tid + 256 * i;
            int ll = e & 63, cc = e >> 6;
            Xs[cc][ll] = X[(size_t)(c0 + cc) * LL + l0 + ll];
        }
        __syncthreads();
#pragma unroll
        for (int kk = 0; kk < 16; ++kk) {
            float a[4], b[4];
#pragma unroll
            for (int i = 0; i < 4; ++i) a[i] = Ws[kk][ty * 4 + i];
#pragma unroll
            for (int j = 0; j < 4; ++j) b[j] = Xs[kk][tx * 4 + j];
#pragma unroll
            for (int i = 0; i < 4; ++i)
#pragma unroll
                for (int j = 0; j < 4; ++j) acc[i][j] += a[i] * b[j];
        }
        __syncthreads();
    }

    if (mat == 2) {
        // vT[n][d][l]
        u16* o = vT + (size_t)n * CH * LL;
#pragma unroll
        for (int i = 0; i < 4; ++i) {
            u32 w0 = pack2(acc[i][0], acc[i][1]);
            u32 w1 = pack2(acc[i][2], acc[i][3]);
            *(uint2*)&o[(size_t)(d0 + ty * 4 + i) * LL + l0 + tx * 4] = make_uint2(w0, w1);
        }
    } else {
        // q or k: [n][l][d]
        u16* o = ((mat == 0) ? q : k) + (size_t)n * LL * CH;
#pragma unroll
        for (int j = 0; j < 4; ++j) {
            u32 w0 = pack2(acc[0][j], acc[1][j]);
            u32 w1 = pack2(acc[2][j], acc[3][j]);
            *(uint2*)&o[(size_t)(l0 + tx * 4 + j) * CH + d0 + ty * 4] = make_uint2(w0, w1);
        }
    }
}

// ---------------------------------------------------------------------------
// Kernel 2: flash attention, key-split. Block = 128 Q rows, 8 waves x 16 rows.
// blockIdx.z = key-split id; each split covers `iters`*32 keys.
// No max-subtraction (scores/16 ~ N(0,1), bounded): p = exp2(s*scale*log2e).
// Row-sum l obtained free via 16 all-ones V rows (17th PV accumulator tile).
// Q fragments loaded directly from global (one-time).
// Writes un-normalized partial O (bf16) + l (fp32); merge kernel combines.
// LDS 48896 B: K[32][264] | V[272][40] | P[128][40]
// ---------------------------------------------------------------------------
#define KSTRIDE 264
#define VSTRIDE 40
#define PSTRIDE 40
#define V_OFF 16896
#define P_OFF 38656

__global__ __launch_bounds__(512, 5) void fattn_kernel(
    const u16* __restrict__ q, const u16* __restrict__ k,
    const u16* __restrict__ vT, u16* __restrict__ Op, float* __restrict__ l_s,
    int iters) {
    const int n = blockIdx.y;
    const int s_id = blockIdx.z;
    const int l0 = blockIdx.x * 128;
    const int m_base = s_id * iters * 32;
    const int tid = threadIdx.x;
    const int w = tid >> 6;          // 0..7
    const int lane = tid & 63;
    const int lhi = lane >> 4, llo = lane & 15;

    __shared__ __align__(16) char smem[48896];
    u16* K_lds = (u16*)smem;            // [32][264]
    u16* V_lds = (u16*)(smem + V_OFF);  // [272][40]; rows 256..271 = 1.0
    u16* P_lds = (u16*)(smem + P_OFF);  // [128][40]

    // ---- ones rows for V (l accumulation) ----
    if (tid < 320) ((u32*)(V_lds + 256 * VSTRIDE))[tid] = 0x3f803f80u;  // bf16 1.0 x2

    // ---- Q fragments (A-layout) direct from global ----
    bf16x8 qf[8];
    {
        const u16* base = q + (size_t)(n * LL + l0 + w * 16 + llo) * CH + lhi * 8;
#pragma unroll
        for (int ks = 0; ks < 8; ++ks) qf[ks] = *(const bf16x8*)(base + ks * 32);
    }

    const u16* kg = k + (size_t)n * LL * CH;
    const u16* vg = vT + (size_t)n * CH * LL;

    // ---- prefetch tile 0 into registers (K: 32x256, V: 256x32, each 1024 u4) ----
    uint4 kb[2], vb[2];
#pragma unroll
    for (int i = 0; i < 2; ++i) {
        int e = tid + i * 512;
        kb[i] = *(const uint4*)(kg + (size_t)(m_base + (e >> 5)) * CH + (e & 31) * 8);
        vb[i] = *(const uint4*)(vg + (size_t)(e >> 2) * LL + m_base + (e & 3) * 8);
    }

    f32x4 oacc[17];
#pragma unroll
    for (int t = 0; t < 17; ++t) oacc[t] = (f32x4){0.f, 0.f, 0.f, 0.f};

    const float C1 = 0.09016844005556021f;  // (1/16) * log2(e)

    for (int it = 0; it < iters; ++it) {
        __syncthreads();  // previous tile's consumers done (also orders ones-init)
#pragma unroll
        for (int i = 0; i < 2; ++i) {
            int e = tid + i * 512;
            *(uint4*)(K_lds + (e >> 5) * KSTRIDE + (e & 31) * 8) = kb[i];
            *(uint4*)(V_lds + (e >> 2) * VSTRIDE + (e & 3) * 8) = vb[i];
        }
        __syncthreads();
        if (it < iters - 1) {
            const int m1 = m_base + (it + 1) * 32;
#pragma unroll
            for (int i = 0; i < 2; ++i) {
                int e = tid + i * 512;
                kb[i] = *(const uint4*)(kg + (size_t)(m1 + (e >> 5)) * CH + (e & 31) * 8);
                vb[i] = *(const uint4*)(vg + (size_t)(e >> 2) * LL + m1 + (e & 3) * 8);
            }
        }

        // ---- S = Q·K^T : 2 col-tiles x 8 k-steps ----
        f32x4 s0 = (f32x4){0.f, 0.f, 0.f, 0.f};
        f32x4 s1 = (f32x4){0.f, 0.f, 0.f, 0.f};
        const u16* kfb = K_lds + llo * KSTRIDE + lhi * 8;
#pragma unroll
        for (int ks = 0; ks < 8; ++ks) {
            bf16x8 b0 = *(const bf16x8*)(kfb + ks * 32);
            bf16x8 b1 = *(const bf16x8*)(kfb + 16 * KSTRIDE + ks * 32);
            s0 = __builtin_amdgcn_mfma_f32_16x16x32_bf16(qf[ks], b0, s0, 0, 0, 0);
            s1 = __builtin_amdgcn_mfma_f32_16x16x32_bf16(qf[ks], b1, s1, 0, 0, 0);
        }

        // ---- p = exp2(s * C1), write to P (bf16, [row][m]) ----
        u16* pw = P_lds + (w * 16) * PSTRIDE;
#pragma unroll
        for (int r = 0; r < 4; ++r) {
            float p0 = __builtin_amdgcn_exp2f(s0[r] * C1);
            float p1 = __builtin_amdgcn_exp2f(s1[r] * C1);
            int lrow = lhi * 4 + r;
            pw[lrow * PSTRIDE + llo] = f2b(p0);
            pw[lrow * PSTRIDE + 16 + llo] = f2b(p1);
        }

        // ---- PV: A = P (wave-private rows), B = V^T fragments; tile 16 = l ----
        bf16x8 pf = *(const bf16x8*)(P_lds + (w * 16 + llo) * PSTRIDE + lhi * 8);
        const u16* vfb = V_lds + llo * VSTRIDE + lhi * 8;
#pragma unroll
        for (int ct = 0; ct < 17; ++ct) {
            bf16x8 vf = *(const bf16x8*)(vfb + ct * 16 * VSTRIDE);
            oacc[ct] = __builtin_amdgcn_mfma_f32_16x16x32_bf16(pf, vf, oacc[ct], 0, 0, 0);
        }
    }

    // ---- epilogue: store un-normalized partial O (bf16) + l (fp32) ----
    u16* ap = Op + (size_t)((s_id * NB + n) * (size_t)LL + l0 + w * 16) * CH;
    float* lp = l_s + (size_t)s_id * NB * LL + (size_t)n * LL + l0 + w * 16;
#pragma unroll
    for (int r = 0; r < 4; ++r) {
        int lrow = lhi * 4 + r;
#pragma unroll
        for (int ct = 0; ct < 16; ++ct) {
            ap[(size_t)lrow * CH + ct * 16 + llo] = f2b(oacc[ct][r]);
        }
        if (llo == 0) lp[lrow] = oacc[16][r];
    }
}

// ---------------------------------------------------------------------------
// Kernel 2b: inv_l[i] = 1 / sum_s l_s[s][i]   (i over N*L)
// ---------------------------------------------------------------------------
__global__ __launch_bounds__(256) void invl_kernel(
    const float* __restrict__ l_s, float* __restrict__ inv_l, int S) {
    const int i = blockIdx.x * 256 + threadIdx.x;
    float t = 0.0f;
    for (int s = 0; s < S; ++s) t += l_s[(size_t)s * NB * LL + i];
    inv_l[i] = 1.0f / t;
}

// ---------------------------------------------------------------------------
// Kernel 2c: merge splits: att[i] = (sum_s Op[s][i]) * inv_l[i>>8]  (bf16)
// one thread = 8 consecutive d's
// ---------------------------------------------------------------------------
__global__ __launch_bounds__(256) void merge_kernel(
    const u16* __restrict__ Op, const float* __restrict__ inv_l,
    u16* __restrict__ att, int S) {
    const size_t t8 = (size_t)blockIdx.x * 256 + threadIdx.x;
    const size_t flat = t8 * 8;
    const float inv = inv_l[flat >> 8];
    float acc[8];
#pragma unroll
    for (int j = 0; j < 8; ++j) acc[j] = 0.0f;
    for (int s = 0; s < S; ++s) {
        uint4 raw = *(const uint4*)(Op + (size_t)s * NB * LL * CH + flat);
        acc[0] += blo(raw.x); acc[1] += bhi(raw.x);
        acc[2] += blo(raw.y); acc[3] += bhi(raw.y);
        acc[4] += blo(raw.z); acc[5] += bhi(raw.z);
        acc[6] += blo(raw.w); acc[7] += bhi(raw.w);
    }
    uint4 o;
    o.x = pack2(acc[0] * inv, acc[1] * inv);
    o.y = pack2(acc[2] * inv, acc[3] * inv);
    o.z = pack2(acc[4] * inv, acc[5] * inv);
    o.w = pack2(acc[6] * inv, acc[7] * inv);
    *(uint4*)(att + flat) = o;
}

// ---------------------------------------------------------------------------
// Kernel 3: y[n,o,l] = sum_d Wo[o,d] * att[n,l,d] ; fused BN partial sums
// grid (L/64, C/64, N), 256 threads
// ---------------------------------------------------------------------------
__global__ __launch_bounds__(256) void out_kernel(
    const float* __restrict__ Wo, const u16* __restrict__ att,
    float* __restrict__ y, float* __restrict__ stats) {
    const int n = blockIdx.z;
    const int o0 = blockIdx.y * 64;
    const int l0 = blockIdx.x * 64;

    __shared__ float Wos[16][68];
    __shared__ float As[16][68];
    __shared__ float red[2][64][16];

    const int tid = threadIdx.x;
    const int tx = tid & 15, ty = tid >> 4;
    const u16* an = att + (size_t)n * LL * CH;

    float acc[4][4];
#pragma unroll
    for (int i = 0; i < 4; ++i)
#pragma unroll
        for (int j = 0; j < 4; ++j) acc[i][j] = 0.0f;

    for (int kt = 0; kt < 16; ++kt) {
        const int dk = kt * 16;
#pragma unroll
        for (int i = 0; i < 4; ++i) {
            int e = tid + 256 * i;
            int dd = e & 15, oo = e >> 4;
            Wos[dd][oo] = Wo[(size_t)(o0 + oo) * CH + dk + dd];
        }
#pragma unroll
        for (int i = 0; i < 4; ++i) {
            int e = tid + 256 * i;
            int dd = e & 15, ll = e >> 4;
            As[dd][ll] = b2f(an[(size_t)(l0 + ll) * CH + dk + dd]);
        }
        __syncthreads();
#pragma unroll
        for (int kk = 0; kk < 16; ++kk) {
            float a[4], b[4];
#pragma unroll
            for (int i = 0; i < 4; ++i) a[i] = Wos[kk][ty * 4 + i];
#pragma unroll
            for (int j = 0; j < 4; ++j) b[j] = As[kk][tx * 4 + j];
#pragma unroll
            for (int i = 0; i < 4; ++i)
#pragma unroll
                for (int j = 0; j < 4; ++j) acc[i][j] += a[i] * b[j];
        }
        __syncthreads();
    }

    float* yn = y + (size_t)n * CH * LL;
    float ts[4], tq[4];
#pragma unroll
    for (int i = 0; i < 4; ++i) { ts[i] = 0.0f; tq[i] = 0.0f; }
#pragma unroll
    for (int i = 0; i < 4; ++i) {
#pragma unroll
        for (int j = 0; j < 4; ++j) {
            float vv = acc[i][j];
            yn[(size_t)(o0 + ty * 4 + i) * LL + l0 + tx * 4 + j] = vv;
            ts[i] += vv;
            tq[i] += vv * vv;
        }
    }
#pragma unroll
    for (int i = 0; i < 4; ++i) {
        red[0][ty * 4 + i][tx] = ts[i];
        red[1][ty * 4 + i][tx] = tq[i];
    }
    __syncthreads();
    if (tid < 64) {
        float sa = 0.0f, qa = 0.0f;
#pragma unroll
        for (int t = 0; t < 16; ++t) { sa += red[0][tid][t]; qa += red[1][tid][t]; }
        atomicAdd(&stats[o0 + tid], sa);
        atomicAdd(&stats[256 + o0 + tid], qa);
    }
}

// ---------------------------------------------------------------------------
// Kernel 4: BN apply (batch stats, biased var) + residual. float4 streaming.
// ---------------------------------------------------------------------------
__global__ __launch_bounds__(256) void bn_kernel(
    const float* __restrict__ x, const float* __restrict__ y,
    const float* __restrict__ stats, const float* __restrict__ gamma,
    const float* __restrict__ beta, float* __restrict__ out) {
    const int idx = blockIdx.x * 256 + threadIdx.x;  // per float4
    const int base = idx * 4;
    const int c = (base >> 12) & 255;  // (base / L) % C
    const float cnt = 1.0f / 16384.0f; // N*L
    float mean = stats[c] * cnt;
    float var = stats[256 + c] * cnt - mean * mean;
    float rstd = rsqrtf(var + 1e-4f);
    float g = gamma[c] * rstd;
    float b = beta[c];
    float4 yv = ((const float4*)y)[idx];
    float4 xv = ((const float4*)x)[idx];
    float4 o;
    o.x = xv.x + (yv.x - mean) * g + b;
    o.y = xv.y + (yv.y - mean) * g + b;
    o.z = xv.z + (yv.z - mean) * g + b;
    o.w = xv.w + (yv.w - mean) * g + b;
    ((float4*)out)[idx] = o;
}

// ---------------------------------------------------------------------------
extern "C" void kernel_launch(void* const* d_in, const int* in_sizes, int n_in,
                              void* d_out, int out_size, void* d_ws, size_t ws_size,
                              hipStream_t stream) {
    const float* x = (const float*)d_in[0];
    const float* Wq = (const float*)d_in[1];
    const float* Wk = (const float*)d_in[2];
    const float* Wv = (const float*)d_in[3];
    const float* Wo = (const float*)d_in[4];
    const float* gamma = (const float*)d_in[5];
    const float* beta = (const float*)d_in[6];
    float* out = (float*)d_out;

    const size_t elems = (size_t)NB * LL * CH;  // 4,194,304

    // pick largest split count whose workspace fits
    int S = 1;
    for (int cand = 8; cand >= 2; cand >>= 1) {
        size_t need = elems * 2 * (size_t)(3 + cand) +
                      (size_t)(cand + 1) * NB * LL * 4 + 4096;
        if (ws_size >= need) { S = cand; break; }
    }
    const int iters = 128 / S;

    char* wsb = (char*)d_ws;
    u16* q = (u16*)wsb;                          // 8.39 MB
    u16* k = q + elems;                          // 8.39 MB
    u16* vT = k + elems;                         // 8.39 MB
    u16* Op = vT + elems;                        // S * 8.39 MB
    float* l_s = (float*)(Op + (size_t)S * elems);        // S * 64 KB
    float* inv_l = l_s + (size_t)S * NB * LL;             // 64 KB
    float* stats = inv_l + (size_t)NB * LL;               // 2 KB
    u16* att = q;                                // reuse q (dead after fattn)
    float* y = (float*)k;                        // reuse k+vT (dead after merge)

    zero_stats<<<1, 512, 0, stream>>>(stats);
    proj_kernel<<<dim3(LL / 64, CH / 64, 12), 256, 0, stream>>>(x, Wq, Wk, Wv, q, k, vT);
    fattn_kernel<<<dim3(LL / 128, NB, S), 512, 0, stream>>>(q, k, vT, Op, l_s, iters);
    invl_kernel<<<(NB * LL) / 256, 256, 0, stream>>>(l_s, inv_l, S);
    merge_kernel<<<(int)(elems / 8 / 256), 256, 0, stream>>>(Op, inv_l, att, S);
    out_kernel<<<dim3(LL / 64, CH / 64, NB), 256, 0, stream>>>(Wo, att, y, stats);
    bn_kernel<<<(NB * CH * LL / 4) / 256, 256, 0, stream>>>(x, y, stats, gamma, beta, out);
}

// Round 5
// 687.639 us; speedup vs baseline: 1.0935x; 1.0935x over previous
//
#include <hip/hip_runtime.h>
#include <cstdint>
#include <cstddef>

// Problem constants: N=4, C=D=256, H=W=64, L=4096
#define NB 4
#define CH 256
#define LL 4096

typedef unsigned short u16;
typedef unsigned int u32;
typedef __attribute__((ext_vector_type(8))) short bf16x8;
typedef __attribute__((ext_vector_type(4))) float f32x4;

__device__ __forceinline__ float blo(u32 x) { return __uint_as_float(x << 16); }
__device__ __forceinline__ float bhi(u32 x) { return __uint_as_float(x & 0xffff0000u); }
__device__ __forceinline__ float b2f(u16 h) { return __uint_as_float(((u32)h) << 16); }
__device__ __forceinline__ u16 f2b(float f) {
    u32 u = __float_as_uint(f);
    u32 r = (u + 0x7fffu + ((u >> 16) & 1u)) >> 16;  // RNE
    return (u16)r;
}
__device__ __forceinline__ u32 pack2(float a, float b) {
    return (u32)f2b(a) | ((u32)f2b(b) << 16);
}

// ---------------------------------------------------------------------------
// Kernel 0: zero BN stats accumulators (512 floats)
// ---------------------------------------------------------------------------
__global__ void zero_stats(float* stats) { stats[threadIdx.x] = 0.0f; }

// ---------------------------------------------------------------------------
// Kernel 1: projections. out[d,l] = sum_c W[d,c] * x[n,c,l]
// grid (L/64, D/64, 12) where z = mat*4 + n ; mat 0=q, 1=k, 2=v
// q,k stored (N,L,D) bf16 ; vT stored (N,D,L) bf16  (MFMA fragment layouts)
// ---------------------------------------------------------------------------
__global__ __launch_bounds__(256) void proj_kernel(
    const float* __restrict__ x, const float* __restrict__ Wq,
    const float* __restrict__ Wk, const float* __restrict__ Wv,
    u16* __restrict__ q, u16* __restrict__ k, u16* __restrict__ vT) {
    const int n = blockIdx.z & 3;
    const int mat = blockIdx.z >> 2;
    const float* W = (mat == 0) ? Wq : ((mat == 1) ? Wk : Wv);
    const int l0 = blockIdx.x * 64;
    const int d0 = blockIdx.y * 64;
    const float* X = x + (size_t)n * CH * LL;

    __shared__ float Ws[16][68];
    __shared__ float Xs[16][68];

    const int tid = threadIdx.x;
    const int tx = tid & 15, ty = tid >> 4;

    float acc[4][4];
#pragma unroll
    for (int i = 0; i < 4; ++i)
#pragma unroll
        for (int j = 0; j < 4; ++j) acc[i][j] = 0.0f;

    for (int kt = 0; kt < 16; ++kt) {
        const int c0 = kt * 16;
#pragma unroll
        for (int i = 0; i < 4; ++i) {
            int e = tid + 256 * i;
            int cc = e & 15, dd = e >> 4;
            Ws[cc][dd] = W[(size_t)(d0 + dd) * CH + c0 + cc];
        }
#pragma unroll
        for (int i = 0; i < 4; ++i) {
            int e = tid + 256 * i;
            int ll = e & 63, cc = e >> 6;
            Xs[cc][ll] = X[(size_t)(c0 + cc) * LL + l0 + ll];
        }
        __syncthreads();
#pragma unroll
        for (int kk = 0; kk < 16; ++kk) {
            float a[4], b[4];
#pragma unroll
            for (int i = 0; i < 4; ++i) a[i] = Ws[kk][ty * 4 + i];
#pragma unroll
            for (int j = 0; j < 4; ++j) b[j] = Xs[kk][tx * 4 + j];
#pragma unroll
            for (int i = 0; i < 4; ++i)
#pragma unroll
                for (int j = 0; j < 4; ++j) acc[i][j] += a[i] * b[j];
        }
        __syncthreads();
    }

    if (mat == 2) {
        // vT[n][d][l]
        u16* o = vT + (size_t)n * CH * LL;
#pragma unroll
        for (int i = 0; i < 4; ++i) {
            u32 w0 = pack2(acc[i][0], acc[i][1]);
            u32 w1 = pack2(acc[i][2], acc[i][3]);
            *(uint2*)&o[(size_t)(d0 + ty * 4 + i) * LL + l0 + tx * 4] = make_uint2(w0, w1);
        }
    } else {
        // q or k: [n][l][d]
        u16* o = ((mat == 0) ? q : k) + (size_t)n * LL * CH;
#pragma unroll
        for (int j = 0; j < 4; ++j) {
            u32 w0 = pack2(acc[0][j], acc[1][j]);
            u32 w1 = pack2(acc[2][j], acc[3][j]);
            *(uint2*)&o[(size_t)(l0 + tx * 4 + j) * CH + d0 + ty * 4] = make_uint2(w0, w1);
        }
    }
}

// ---------------------------------------------------------------------------
// Kernel 2: flash attention, key-split. Block = 64 Q rows, 4 waves x 16 rows.
// blockIdx.z = key-split id; each split covers `iters`*32 keys.
// No max-subtraction (scores/16 ~ N(0,1), bounded): p = exp2(s*scale*log2e).
// Row-sum l accumulated in VALU (lrun), shuffle-reduced once at the end.
// Q fragments loaded directly from global (one-time).
// Writes un-normalized partial O (bf16) + l (fp32); merge kernel combines.
// NOTE: NO min-occupancy in __launch_bounds__ — (256,3)/(512,5) forced
// VGPR 84/48 and spilled the accumulators (R3/R4: 742 MB scratch writes).
// LDS 45056 B: K[32][264] | V[256][44] | P[64][44]  -> 3 blocks/CU
// ---------------------------------------------------------------------------
#define KSTRIDE 264
#define VSTRIDE 44
#define PSTRIDE 44
#define V_OFF 16896
#define P_OFF 39424

__global__ __launch_bounds__(256) void fattn_kernel(
    const u16* __restrict__ q, const u16* __restrict__ k,
    const u16* __restrict__ vT, u16* __restrict__ Op, float* __restrict__ l_s,
    int iters) {
    const int n = blockIdx.y;
    const int s_id = blockIdx.z;
    const int l0 = blockIdx.x * 64;
    const int m_base = s_id * iters * 32;
    const int tid = threadIdx.x;
    const int w = tid >> 6;
    const int lane = tid & 63;
    const int lhi = lane >> 4, llo = lane & 15;

    __shared__ __align__(16) char smem[45056];
    u16* K_lds = (u16*)smem;            // [32][264]
    u16* V_lds = (u16*)(smem + V_OFF);  // [256][44]
    u16* P_lds = (u16*)(smem + P_OFF);  // [64][44]

    // ---- Q fragments (A-layout) direct from global ----
    bf16x8 qf[8];
    {
        const u16* base = q + (size_t)(n * LL + l0 + w * 16 + llo) * CH + lhi * 8;
#pragma unroll
        for (int ks = 0; ks < 8; ++ks) qf[ks] = *(const bf16x8*)(base + ks * 32);
    }

    const u16* kg = k + (size_t)n * LL * CH;
    const u16* vg = vT + (size_t)n * CH * LL;

    // ---- prefetch tile 0 into registers (K: 32x256, V: 256x32) ----
    uint4 kb[4], vb[4];
#pragma unroll
    for (int i = 0; i < 4; ++i) {
        int e = tid + i * 256;
        kb[i] = *(const uint4*)(kg + (size_t)(m_base + (e >> 5)) * CH + (e & 31) * 8);
        vb[i] = *(const uint4*)(vg + (size_t)(e >> 2) * LL + m_base + (e & 3) * 8);
    }

    f32x4 oacc[16];
#pragma unroll
    for (int t = 0; t < 16; ++t) oacc[t] = (f32x4){0.f, 0.f, 0.f, 0.f};
    float lrun[4] = {0.f, 0.f, 0.f, 0.f};

    const float C1 = 0.09016844005556021f;  // (1/16) * log2(e)

    for (int it = 0; it < iters; ++it) {
        __syncthreads();  // previous tile's consumers done
#pragma unroll
        for (int i = 0; i < 4; ++i) {
            int e = tid + i * 256;
            *(uint4*)(K_lds + (e >> 5) * KSTRIDE + (e & 31) * 8) = kb[i];
            *(uint4*)(V_lds + (e >> 2) * VSTRIDE + (e & 3) * 8) = vb[i];
        }
        __syncthreads();
        if (it < iters - 1) {
            const int m1 = m_base + (it + 1) * 32;
#pragma unroll
            for (int i = 0; i < 4; ++i) {
                int e = tid + i * 256;
                kb[i] = *(const uint4*)(kg + (size_t)(m1 + (e >> 5)) * CH + (e & 31) * 8);
                vb[i] = *(const uint4*)(vg + (size_t)(e >> 2) * LL + m1 + (e & 3) * 8);
            }
        }

        // ---- S = Q·K^T : 2 col-tiles x 8 k-steps ----
        f32x4 s0 = (f32x4){0.f, 0.f, 0.f, 0.f};
        f32x4 s1 = (f32x4){0.f, 0.f, 0.f, 0.f};
        const u16* kfb = K_lds + llo * KSTRIDE + lhi * 8;
#pragma unroll
        for (int ks = 0; ks < 8; ++ks) {
            bf16x8 b0 = *(const bf16x8*)(kfb + ks * 32);
            bf16x8 b1 = *(const bf16x8*)(kfb + 16 * KSTRIDE + ks * 32);
            s0 = __builtin_amdgcn_mfma_f32_16x16x32_bf16(qf[ks], b0, s0, 0, 0, 0);
            s1 = __builtin_amdgcn_mfma_f32_16x16x32_bf16(qf[ks], b1, s1, 0, 0, 0);
        }

        // ---- p = exp2(s * C1), write to P (bf16, [row][m]); lrun += p ----
        u16* pw = P_lds + (w * 16) * PSTRIDE;
#pragma unroll
        for (int r = 0; r < 4; ++r) {
            float p0 = __builtin_amdgcn_exp2f(s0[r] * C1);
            float p1 = __builtin_amdgcn_exp2f(s1[r] * C1);
            int lrow = lhi * 4 + r;
            pw[lrow * PSTRIDE + llo] = f2b(p0);
            pw[lrow * PSTRIDE + 16 + llo] = f2b(p1);
            lrun[r] += p0 + p1;
        }

        // ---- PV: A = P (wave-private rows), B = V^T fragments ----
        bf16x8 pf = *(const bf16x8*)(P_lds + (w * 16 + llo) * PSTRIDE + lhi * 8);
        const u16* vfb = V_lds + llo * VSTRIDE + lhi * 8;
#pragma unroll
        for (int ct = 0; ct < 16; ++ct) {
            bf16x8 vf = *(const bf16x8*)(vfb + ct * 16 * VSTRIDE);
            oacc[ct] = __builtin_amdgcn_mfma_f32_16x16x32_bf16(pf, vf, oacc[ct], 0, 0, 0);
        }
    }

    // ---- epilogue: store un-normalized partial O (bf16) + l (fp32) ----
    u16* ap = Op + (size_t)((s_id * NB + n) * (size_t)LL + l0 + w * 16) * CH;
    float* lp = l_s + (size_t)s_id * NB * LL + (size_t)n * LL + l0 + w * 16;
#pragma unroll
    for (int r = 0; r < 4; ++r) {
        // reduce lrun over the 16-lane llo group (row = w*16 + lhi*4 + r)
        float t = lrun[r];
        t += __shfl_xor(t, 1);
        t += __shfl_xor(t, 2);
        t += __shfl_xor(t, 4);
        t += __shfl_xor(t, 8);
        int lrow = lhi * 4 + r;
#pragma unroll
        for (int ct = 0; ct < 16; ++ct) {
            ap[(size_t)lrow * CH + ct * 16 + llo] = f2b(oacc[ct][r]);
        }
        if (llo == 0) lp[lrow] = t;
    }
}

// ---------------------------------------------------------------------------
// Kernel 2c: merge splits: att[i] = (sum_s Op[s][i]) / (sum_s l_s[s][row])
// one thread = 8 consecutive d's. invl computed inline (L2-hit loads).
// ---------------------------------------------------------------------------
__global__ __launch_bounds__(256) void merge_kernel(
    const u16* __restrict__ Op, const float* __restrict__ l_s,
    u16* __restrict__ att, int S) {
    const size_t t8 = (size_t)blockIdx.x * 256 + threadIdx.x;
    const size_t flat = t8 * 8;
    const size_t row = flat >> 8;
    float lsum = 0.0f;
    for (int s = 0; s < S; ++s) lsum += l_s[(size_t)s * NB * LL + row];
    const float inv = 1.0f / lsum;
    float acc[8];
#pragma unroll
    for (int j = 0; j < 8; ++j) acc[j] = 0.0f;
    for (int s = 0; s < S; ++s) {
        uint4 raw = *(const uint4*)(Op + (size_t)s * NB * LL * CH + flat);
        acc[0] += blo(raw.x); acc[1] += bhi(raw.x);
        acc[2] += blo(raw.y); acc[3] += bhi(raw.y);
        acc[4] += blo(raw.z); acc[5] += bhi(raw.z);
        acc[6] += blo(raw.w); acc[7] += bhi(raw.w);
    }
    uint4 o;
    o.x = pack2(acc[0] * inv, acc[1] * inv);
    o.y = pack2(acc[2] * inv, acc[3] * inv);
    o.z = pack2(acc[4] * inv, acc[5] * inv);
    o.w = pack2(acc[6] * inv, acc[7] * inv);
    *(uint4*)(att + flat) = o;
}

// ---------------------------------------------------------------------------
// Kernel 3: y[n,o,l] = sum_d Wo[o,d] * att[n,l,d] ; fused BN partial sums
// grid (L/64, C/64, N), 256 threads
// ---------------------------------------------------------------------------
__global__ __launch_bounds__(256) void out_kernel(
    const float* __restrict__ Wo, const u16* __restrict__ att,
    float* __restrict__ y, float* __restrict__ stats) {
    const int n = blockIdx.z;
    const int o0 = blockIdx.y * 64;
    const int l0 = blockIdx.x * 64;

    __shared__ float Wos[16][68];
    __shared__ float As[16][68];
    __shared__ float red[2][64][16];

    const int tid = threadIdx.x;
    const int tx = tid & 15, ty = tid >> 4;
    const u16* an = att + (size_t)n * LL * CH;

    float acc[4][4];
#pragma unroll
    for (int i = 0; i < 4; ++i)
#pragma unroll
        for (int j = 0; j < 4; ++j) acc[i][j] = 0.0f;

    for (int kt = 0; kt < 16; ++kt) {
        const int dk = kt * 16;
#pragma unroll
        for (int i = 0; i < 4; ++i) {
            int e = tid + 256 * i;
            int dd = e & 15, oo = e >> 4;
            Wos[dd][oo] = Wo[(size_t)(o0 + oo) * CH + dk + dd];
        }
#pragma unroll
        for (int i = 0; i < 4; ++i) {
            int e = tid + 256 * i;
            int dd = e & 15, ll = e >> 4;
            As[dd][ll] = b2f(an[(size_t)(l0 + ll) * CH + dk + dd]);
        }
        __syncthreads();
#pragma unroll
        for (int kk = 0; kk < 16; ++kk) {
            float a[4], b[4];
#pragma unroll
            for (int i = 0; i < 4; ++i) a[i] = Wos[kk][ty * 4 + i];
#pragma unroll
            for (int j = 0; j < 4; ++j) b[j] = As[kk][tx * 4 + j];
#pragma unroll
            for (int i = 0; i < 4; ++i)
#pragma unroll
                for (int j = 0; j < 4; ++j) acc[i][j] += a[i] * b[j];
        }
        __syncthreads();
    }

    float* yn = y + (size_t)n * CH * LL;
    float ts[4], tq[4];
#pragma unroll
    for (int i = 0; i < 4; ++i) { ts[i] = 0.0f; tq[i] = 0.0f; }
#pragma unroll
    for (int i = 0; i < 4; ++i) {
#pragma unroll
        for (int j = 0; j < 4; ++j) {
            float vv = acc[i][j];
            yn[(size_t)(o0 + ty * 4 + i) * LL + l0 + tx * 4 + j] = vv;
            ts[i] += vv;
            tq[i] += vv * vv;
        }
    }
#pragma unroll
    for (int i = 0; i < 4; ++i) {
        red[0][ty * 4 + i][tx] = ts[i];
        red[1][ty * 4 + i][tx] = tq[i];
    }
    __syncthreads();
    if (tid < 64) {
        float sa = 0.0f, qa = 0.0f;
#pragma unroll
        for (int t = 0; t < 16; ++t) { sa += red[0][tid][t]; qa += red[1][tid][t]; }
        atomicAdd(&stats[o0 + tid], sa);
        atomicAdd(&stats[256 + o0 + tid], qa);
    }
}

// ---------------------------------------------------------------------------
// Kernel 4: BN apply (batch stats, biased var) + residual. float4 streaming.
// ---------------------------------------------------------------------------
__global__ __launch_bounds__(256) void bn_kernel(
    const float* __restrict__ x, const float* __restrict__ y,
    const float* __restrict__ stats, const float* __restrict__ gamma,
    const float* __restrict__ beta, float* __restrict__ out) {
    const int idx = blockIdx.x * 256 + threadIdx.x;  // per float4
    const int base = idx * 4;
    const int c = (base >> 12) & 255;  // (base / L) % C
    const float cnt = 1.0f / 16384.0f; // N*L
    float mean = stats[c] * cnt;
    float var = stats[256 + c] * cnt - mean * mean;
    float rstd = rsqrtf(var + 1e-4f);
    float g = gamma[c] * rstd;
    float b = beta[c];
    float4 yv = ((const float4*)y)[idx];
    float4 xv = ((const float4*)x)[idx];
    float4 o;
    o.x = xv.x + (yv.x - mean) * g + b;
    o.y = xv.y + (yv.y - mean) * g + b;
    o.z = xv.z + (yv.z - mean) * g + b;
    o.w = xv.w + (yv.w - mean) * g + b;
    ((float4*)out)[idx] = o;
}

// ---------------------------------------------------------------------------
extern "C" void kernel_launch(void* const* d_in, const int* in_sizes, int n_in,
                              void* d_out, int out_size, void* d_ws, size_t ws_size,
                              hipStream_t stream) {
    const float* x = (const float*)d_in[0];
    const float* Wq = (const float*)d_in[1];
    const float* Wk = (const float*)d_in[2];
    const float* Wv = (const float*)d_in[3];
    const float* Wo = (const float*)d_in[4];
    const float* gamma = (const float*)d_in[5];
    const float* beta = (const float*)d_in[6];
    float* out = (float*)d_out;

    const size_t elems = (size_t)NB * LL * CH;  // 4,194,304

    // pick largest split count whose workspace fits
    int S = 1;
    for (int cand = 8; cand >= 2; cand >>= 1) {
        size_t need = elems * 2 * (size_t)(3 + cand) +
                      (size_t)cand * NB * LL * 4 + 4096;
        if (ws_size >= need) { S = cand; break; }
    }
    const int iters = 128 / S;

    char* wsb = (char*)d_ws;
    u16* q = (u16*)wsb;                          // 8.39 MB
    u16* k = q + elems;                          // 8.39 MB
    u16* vT = k + elems;                         // 8.39 MB
    u16* Op = vT + elems;                        // S * 8.39 MB
    float* l_s = (float*)(Op + (size_t)S * elems);        // S * 64 KB
    float* stats = l_s + (size_t)S * NB * LL;             // 2 KB
    u16* att = q;                                // reuse q (dead after fattn)
    float* y = (float*)k;                        // reuse k+vT (dead after merge)

    zero_stats<<<1, 512, 0, stream>>>(stats);
    proj_kernel<<<dim3(LL / 64, CH / 64, 12), 256, 0, stream>>>(x, Wq, Wk, Wv, q, k, vT);
    fattn_kernel<<<dim3(LL / 64, NB, S), 256, 0, stream>>>(q, k, vT, Op, l_s, iters);
    merge_kernel<<<(int)(elems / 8 / 256), 256, 0, stream>>>(Op, l_s, att, S);
    out_kernel<<<dim3(LL / 64, CH / 64, NB), 256, 0, stream>>>(Wo, att, y, stats);
    bn_kernel<<<(NB * CH * LL / 4) / 256, 256, 0, stream>>>(x, y, stats, gamma, beta, out);
}

// Round 6
// 678.587 us; speedup vs baseline: 1.1081x; 1.0133x over previous
//
#include <hip/hip_runtime.h>
#include <cstdint>
#include <cstddef>

// Problem constants: N=4, C=D=256, H=W=64, L=4096
#define NB 4
#define CH 256
#define LL 4096

typedef unsigned short u16;
typedef unsigned int u32;
typedef __attribute__((ext_vector_type(8))) short bf16x8;
typedef __attribute__((ext_vector_type(4))) float f32x4;

__device__ __forceinline__ float blo(u32 x) { return __uint_as_float(x << 16); }
__device__ __forceinline__ float bhi(u32 x) { return __uint_as_float(x & 0xffff0000u); }
__device__ __forceinline__ float b2f(u16 h) { return __uint_as_float(((u32)h) << 16); }
__device__ __forceinline__ u16 f2b(float f) {
    u32 u = __float_as_uint(f);
    u32 r = (u + 0x7fffu + ((u >> 16) & 1u)) >> 16;  // RNE
    return (u16)r;
}
__device__ __forceinline__ u32 pack2(float a, float b) {
    return (u32)f2b(a) | ((u32)f2b(b) << 16);
}

// ---------------------------------------------------------------------------
// Kernel 0: zero BN stats accumulators (512 floats)
// ---------------------------------------------------------------------------
__global__ void zero_stats(float* stats) { stats[threadIdx.x] = 0.0f; }

// ---------------------------------------------------------------------------
// Kernel 1: projections. out[d,l] = sum_c W[d,c] * x[n,c,l]
// grid (L/64, D/64, 12) where z = mat*4 + n ; mat 0=q, 1=k, 2=v
// q,k stored (N,L,D) bf16 ; vT stored (N,D,L) bf16  (MFMA fragment layouts)
// ---------------------------------------------------------------------------
__global__ __launch_bounds__(256) void proj_kernel(
    const float* __restrict__ x, const float* __restrict__ Wq,
    const float* __restrict__ Wk, const float* __restrict__ Wv,
    u16* __restrict__ q, u16* __restrict__ k, u16* __restrict__ vT) {
    const int n = blockIdx.z & 3;
    const int mat = blockIdx.z >> 2;
    const float* W = (mat == 0) ? Wq : ((mat == 1) ? Wk : Wv);
    const int l0 = blockIdx.x * 64;
    const int d0 = blockIdx.y * 64;
    const float* X = x + (size_t)n * CH * LL;

    __shared__ float Ws[16][68];
    __shared__ float Xs[16][68];

    const int tid = threadIdx.x;
    const int tx = tid & 15, ty = tid >> 4;

    float acc[4][4];
#pragma unroll
    for (int i = 0; i < 4; ++i)
#pragma unroll
        for (int j = 0; j < 4; ++j) acc[i][j] = 0.0f;

    for (int kt = 0; kt < 16; ++kt) {
        const int c0 = kt * 16;
#pragma unroll
        for (int i = 0; i < 4; ++i) {
            int e = tid + 256 * i;
            int cc = e & 15, dd = e >> 4;
            Ws[cc][dd] = W[(size_t)(d0 + dd) * CH + c0 + cc];
        }
#pragma unroll
        for (int i = 0; i < 4; ++i) {
            int e = tid + 256 * i;
            int ll = e & 63, cc = e >> 6;
            Xs[cc][ll] = X[(size_t)(c0 + cc) * LL + l0 + ll];
        }
        __syncthreads();
#pragma unroll
        for (int kk = 0; kk < 16; ++kk) {
            float a[4], b[4];
#pragma unroll
            for (int i = 0; i < 4; ++i) a[i] = Ws[kk][ty * 4 + i];
#pragma unroll
            for (int j = 0; j < 4; ++j) b[j] = Xs[kk][tx * 4 + j];
#pragma unroll
            for (int i = 0; i < 4; ++i)
#pragma unroll
                for (int j = 0; j < 4; ++j) acc[i][j] += a[i] * b[j];
        }
        __syncthreads();
    }

    if (mat == 2) {
        // vT[n][d][l]
        u16* o = vT + (size_t)n * CH * LL;
#pragma unroll
        for (int i = 0; i < 4; ++i) {
            u32 w0 = pack2(acc[i][0], acc[i][1]);
            u32 w1 = pack2(acc[i][2], acc[i][3]);
            *(uint2*)&o[(size_t)(d0 + ty * 4 + i) * LL + l0 + tx * 4] = make_uint2(w0, w1);
        }
    } else {
        // q or k: [n][l][d]
        u16* o = ((mat == 0) ? q : k) + (size_t)n * LL * CH;
#pragma unroll
        for (int j = 0; j < 4; ++j) {
            u32 w0 = pack2(acc[0][j], acc[1][j]);
            u32 w1 = pack2(acc[2][j], acc[3][j]);
            *(uint2*)&o[(size_t)(l0 + tx * 4 + j) * CH + d0 + ty * 4] = make_uint2(w0, w1);
        }
    }
}

// ---------------------------------------------------------------------------
// Kernel 2: flash attention, key-split. Block = 64 Q rows, 4 waves x 16 rows.
// blockIdx.z = key-split id; each split covers `iters`*32 keys.
// No max-subtraction (scores/16 ~ N(0,1), bounded): p = exp2(s*scale*log2e).
// Row-sum l accumulated in VALU (lrun), shuffle-reduced once at the end.
// Q fragments loaded directly from global (one-time).
// Writes un-normalized partial O (bf16) + l (fp32); merge kernel combines.
// VGPR NOTE (measured ladder): (256,1) -> 116 VGPR, no spill (R2, 20 MB wr);
// (256,3) -> 84, (512,5) -> 48, bare (256) -> 88 -- all spill oacc/qf in the
// K-loop (714-742 MB scratch writes). (256,1) is the ONLY spill-free config.
// LDS 45056 B: K[32][264] | V[256][44] | P[64][44]  -> 3 blocks/CU
// ---------------------------------------------------------------------------
#define KSTRIDE 264
#define VSTRIDE 44
#define PSTRIDE 44
#define V_OFF 16896
#define P_OFF 39424

__global__ __launch_bounds__(256, 1) void fattn_kernel(
    const u16* __restrict__ q, const u16* __restrict__ k,
    const u16* __restrict__ vT, u16* __restrict__ Op, float* __restrict__ l_s,
    int iters) {
    const int n = blockIdx.y;
    const int s_id = blockIdx.z;
    const int l0 = blockIdx.x * 64;
    const int m_base = s_id * iters * 32;
    const int tid = threadIdx.x;
    const int w = tid >> 6;
    const int lane = tid & 63;
    const int lhi = lane >> 4, llo = lane & 15;

    __shared__ __align__(16) char smem[45056];
    u16* K_lds = (u16*)smem;            // [32][264]
    u16* V_lds = (u16*)(smem + V_OFF);  // [256][44]
    u16* P_lds = (u16*)(smem + P_OFF);  // [64][44]

    // ---- Q fragments (A-layout) direct from global ----
    bf16x8 qf[8];
    {
        const u16* base = q + (size_t)(n * LL + l0 + w * 16 + llo) * CH + lhi * 8;
#pragma unroll
        for (int ks = 0; ks < 8; ++ks) qf[ks] = *(const bf16x8*)(base + ks * 32);
    }

    const u16* kg = k + (size_t)n * LL * CH;
    const u16* vg = vT + (size_t)n * CH * LL;

    // ---- prefetch tile 0 into registers (K: 32x256, V: 256x32) ----
    uint4 kb[4], vb[4];
#pragma unroll
    for (int i = 0; i < 4; ++i) {
        int e = tid + i * 256;
        kb[i] = *(const uint4*)(kg + (size_t)(m_base + (e >> 5)) * CH + (e & 31) * 8);
        vb[i] = *(const uint4*)(vg + (size_t)(e >> 2) * LL + m_base + (e & 3) * 8);
    }

    f32x4 oacc[16];
#pragma unroll
    for (int t = 0; t < 16; ++t) oacc[t] = (f32x4){0.f, 0.f, 0.f, 0.f};
    float lrun[4] = {0.f, 0.f, 0.f, 0.f};

    const float C1 = 0.09016844005556021f;  // (1/16) * log2(e)

    for (int it = 0; it < iters; ++it) {
        __syncthreads();  // previous tile's consumers done
#pragma unroll
        for (int i = 0; i < 4; ++i) {
            int e = tid + i * 256;
            *(uint4*)(K_lds + (e >> 5) * KSTRIDE + (e & 31) * 8) = kb[i];
            *(uint4*)(V_lds + (e >> 2) * VSTRIDE + (e & 3) * 8) = vb[i];
        }
        __syncthreads();
        if (it < iters - 1) {
            const int m1 = m_base + (it + 1) * 32;
#pragma unroll
            for (int i = 0; i < 4; ++i) {
                int e = tid + i * 256;
                kb[i] = *(const uint4*)(kg + (size_t)(m1 + (e >> 5)) * CH + (e & 31) * 8);
                vb[i] = *(const uint4*)(vg + (size_t)(e >> 2) * LL + m1 + (e & 3) * 8);
            }
        }

        // ---- S = Q·K^T : 2 col-tiles x 8 k-steps ----
        f32x4 s0 = (f32x4){0.f, 0.f, 0.f, 0.f};
        f32x4 s1 = (f32x4){0.f, 0.f, 0.f, 0.f};
        const u16* kfb = K_lds + llo * KSTRIDE + lhi * 8;
#pragma unroll
        for (int ks = 0; ks < 8; ++ks) {
            bf16x8 b0 = *(const bf16x8*)(kfb + ks * 32);
            bf16x8 b1 = *(const bf16x8*)(kfb + 16 * KSTRIDE + ks * 32);
            s0 = __builtin_amdgcn_mfma_f32_16x16x32_bf16(qf[ks], b0, s0, 0, 0, 0);
            s1 = __builtin_amdgcn_mfma_f32_16x16x32_bf16(qf[ks], b1, s1, 0, 0, 0);
        }

        // ---- p = exp2(s * C1), write to P (bf16, [row][m]); lrun += p ----
        u16* pw = P_lds + (w * 16) * PSTRIDE;
#pragma unroll
        for (int r = 0; r < 4; ++r) {
            float p0 = __builtin_amdgcn_exp2f(s0[r] * C1);
            float p1 = __builtin_amdgcn_exp2f(s1[r] * C1);
            int lrow = lhi * 4 + r;
            pw[lrow * PSTRIDE + llo] = f2b(p0);
            pw[lrow * PSTRIDE + 16 + llo] = f2b(p1);
            lrun[r] += p0 + p1;
        }

        // ---- PV: A = P (wave-private rows), B = V^T fragments ----
        bf16x8 pf = *(const bf16x8*)(P_lds + (w * 16 + llo) * PSTRIDE + lhi * 8);
        const u16* vfb = V_lds + llo * VSTRIDE + lhi * 8;
#pragma unroll
        for (int ct = 0; ct < 16; ++ct) {
            bf16x8 vf = *(const bf16x8*)(vfb + ct * 16 * VSTRIDE);
            oacc[ct] = __builtin_amdgcn_mfma_f32_16x16x32_bf16(pf, vf, oacc[ct], 0, 0, 0);
        }
    }

    // ---- epilogue: store un-normalized partial O (bf16) + l (fp32) ----
    u16* ap = Op + (size_t)((s_id * NB + n) * (size_t)LL + l0 + w * 16) * CH;
    float* lp = l_s + (size_t)s_id * NB * LL + (size_t)n * LL + l0 + w * 16;
#pragma unroll
    for (int r = 0; r < 4; ++r) {
        // reduce lrun over the 16-lane llo group (row = w*16 + lhi*4 + r)
        float t = lrun[r];
        t += __shfl_xor(t, 1);
        t += __shfl_xor(t, 2);
        t += __shfl_xor(t, 4);
        t += __shfl_xor(t, 8);
        int lrow = lhi * 4 + r;
#pragma unroll
        for (int ct = 0; ct < 16; ++ct) {
            ap[(size_t)lrow * CH + ct * 16 + llo] = f2b(oacc[ct][r]);
        }
        if (llo == 0) lp[lrow] = t;
    }
}

// ---------------------------------------------------------------------------
// Kernel 2c: merge splits: att[i] = (sum_s Op[s][i]) / (sum_s l_s[s][row])
// one thread = 8 consecutive d's. invl computed inline (L2-hit loads).
// ---------------------------------------------------------------------------
__global__ __launch_bounds__(256) void merge_kernel(
    const u16* __restrict__ Op, const float* __restrict__ l_s,
    u16* __restrict__ att, int S) {
    const size_t t8 = (size_t)blockIdx.x * 256 + threadIdx.x;
    const size_t flat = t8 * 8;
    const size_t row = flat >> 8;
    float lsum = 0.0f;
    for (int s = 0; s < S; ++s) lsum += l_s[(size_t)s * NB * LL + row];
    const float inv = 1.0f / lsum;
    float acc[8];
#pragma unroll
    for (int j = 0; j < 8; ++j) acc[j] = 0.0f;
    for (int s = 0; s < S; ++s) {
        uint4 raw = *(const uint4*)(Op + (size_t)s * NB * LL * CH + flat);
        acc[0] += blo(raw.x); acc[1] += bhi(raw.x);
        acc[2] += blo(raw.y); acc[3] += bhi(raw.y);
        acc[4] += blo(raw.z); acc[5] += bhi(raw.z);
        acc[6] += blo(raw.w); acc[7] += bhi(raw.w);
    }
    uint4 o;
    o.x = pack2(acc[0] * inv, acc[1] * inv);
    o.y = pack2(acc[2] * inv, acc[3] * inv);
    o.z = pack2(acc[4] * inv, acc[5] * inv);
    o.w = pack2(acc[6] * inv, acc[7] * inv);
    *(uint4*)(att + flat) = o;
}

// ---------------------------------------------------------------------------
// Kernel 3: y[n,o,l] = sum_d Wo[o,d] * att[n,l,d] ; fused BN partial sums
// grid (L/64, C/64, N), 256 threads
// ---------------------------------------------------------------------------
__global__ __launch_bounds__(256) void out_kernel(
    const float* __restrict__ Wo, const u16* __restrict__ att,
    float* __restrict__ y, float* __restrict__ stats) {
    const int n = blockIdx.z;
    const int o0 = blockIdx.y * 64;
    const int l0 = blockIdx.x * 64;

    __shared__ float Wos[16][68];
    __shared__ float As[16][68];
    __shared__ float red[2][64][16];

    const int tid = threadIdx.x;
    const int tx = tid & 15, ty = tid >> 4;
    const u16* an = att + (size_t)n * LL * CH;

    float acc[4][4];
#pragma unroll
    for (int i = 0; i < 4; ++i)
#pragma unroll
        for (int j = 0; j < 4; ++j) acc[i][j] = 0.0f;

    for (int kt = 0; kt < 16; ++kt) {
        const int dk = kt * 16;
#pragma unroll
        for (int i = 0; i < 4; ++i) {
            int e = tid + 256 * i;
            int dd = e & 15, oo = e >> 4;
            Wos[dd][oo] = Wo[(size_t)(o0 + oo) * CH + dk + dd];
        }
#pragma unroll
        for (int i = 0; i < 4; ++i) {
            int e = tid + 256 * i;
            int dd = e & 15, ll = e >> 4;
            As[dd][ll] = b2f(an[(size_t)(l0 + ll) * CH + dk + dd]);
        }
        __syncthreads();
#pragma unroll
        for (int kk = 0; kk < 16; ++kk) {
            float a[4], b[4];
#pragma unroll
            for (int i = 0; i < 4; ++i) a[i] = Wos[kk][ty * 4 + i];
#pragma unroll
            for (int j = 0; j < 4; ++j) b[j] = As[kk][tx * 4 + j];
#pragma unroll
            for (int i = 0; i < 4; ++i)
#pragma unroll
                for (int j = 0; j < 4; ++j) acc[i][j] += a[i] * b[j];
        }
        __syncthreads();
    }

    float* yn = y + (size_t)n * CH * LL;
    float ts[4], tq[4];
#pragma unroll
    for (int i = 0; i < 4; ++i) { ts[i] = 0.0f; tq[i] = 0.0f; }
#pragma unroll
    for (int i = 0; i < 4; ++i) {
#pragma unroll
        for (int j = 0; j < 4; ++j) {
            float vv = acc[i][j];
            yn[(size_t)(o0 + ty * 4 + i) * LL + l0 + tx * 4 + j] = vv;
            ts[i] += vv;
            tq[i] += vv * vv;
        }
    }
#pragma unroll
    for (int i = 0; i < 4; ++i) {
        red[0][ty * 4 + i][tx] = ts[i];
        red[1][ty * 4 + i][tx] = tq[i];
    }
    __syncthreads();
    if (tid < 64) {
        float sa = 0.0f, qa = 0.0f;
#pragma unroll
        for (int t = 0; t < 16; ++t) { sa += red[0][tid][t]; qa += red[1][tid][t]; }
        atomicAdd(&stats[o0 + tid], sa);
        atomicAdd(&stats[256 + o0 + tid], qa);
    }
}

// ---------------------------------------------------------------------------
// Kernel 4: BN apply (batch stats, biased var) + residual. float4 streaming.
// ---------------------------------------------------------------------------
__global__ __launch_bounds__(256) void bn_kernel(
    const float* __restrict__ x, const float* __restrict__ y,
    const float* __restrict__ stats, const float* __restrict__ gamma,
    const float* __restrict__ beta, float* __restrict__ out) {
    const int idx = blockIdx.x * 256 + threadIdx.x;  // per float4
    const int base = idx * 4;
    const int c = (base >> 12) & 255;  // (base / L) % C
    const float cnt = 1.0f / 16384.0f; // N*L
    float mean = stats[c] * cnt;
    float var = stats[256 + c] * cnt - mean * mean;
    float rstd = rsqrtf(var + 1e-4f);
    float g = gamma[c] * rstd;
    float b = beta[c];
    float4 yv = ((const float4*)y)[idx];
    float4 xv = ((const float4*)x)[idx];
    float4 o;
    o.x = xv.x + (yv.x - mean) * g + b;
    o.y = xv.y + (yv.y - mean) * g + b;
    o.z = xv.z + (yv.z - mean) * g + b;
    o.w = xv.w + (yv.w - mean) * g + b;
    ((float4*)out)[idx] = o;
}

// ---------------------------------------------------------------------------
extern "C" void kernel_launch(void* const* d_in, const int* in_sizes, int n_in,
                              void* d_out, int out_size, void* d_ws, size_t ws_size,
                              hipStream_t stream) {
    const float* x = (const float*)d_in[0];
    const float* Wq = (const float*)d_in[1];
    const float* Wk = (const float*)d_in[2];
    const float* Wv = (const float*)d_in[3];
    const float* Wo = (const float*)d_in[4];
    const float* gamma = (const float*)d_in[5];
    const float* beta = (const float*)d_in[6];
    float* out = (float*)d_out;

    const size_t elems = (size_t)NB * LL * CH;  // 4,194,304

    // pick largest split count whose workspace fits
    int S = 1;
    for (int cand = 8; cand >= 2; cand >>= 1) {
        size_t need = elems * 2 * (size_t)(3 + cand) +
                      (size_t)cand * NB * LL * 4 + 4096;
        if (ws_size >= need) { S = cand; break; }
    }
    const int iters = 128 / S;

    char* wsb = (char*)d_ws;
    u16* q = (u16*)wsb;                          // 8.39 MB
    u16* k = q + elems;                          // 8.39 MB
    u16* vT = k + elems;                         // 8.39 MB
    u16* Op = vT + elems;                        // S * 8.39 MB
    float* l_s = (float*)(Op + (size_t)S * elems);        // S * 64 KB
    float* stats = l_s + (size_t)S * NB * LL;             // 2 KB
    u16* att = q;                                // reuse q (dead after fattn)
    float* y = (float*)k;                        // reuse k+vT (dead after merge)

    zero_stats<<<1, 512, 0, stream>>>(stats);
    proj_kernel<<<dim3(LL / 64, CH / 64, 12), 256, 0, stream>>>(x, Wq, Wk, Wv, q, k, vT);
    fattn_kernel<<<dim3(LL / 64, NB, S), 256, 0, stream>>>(q, k, vT, Op, l_s, iters);
    merge_kernel<<<(int)(elems / 8 / 256), 256, 0, stream>>>(Op, l_s, att, S);
    out_kernel<<<dim3(LL / 64, CH / 64, NB), 256, 0, stream>>>(Wo, att, y, stats);
    bn_kernel<<<(NB * CH * LL / 4) / 256, 256, 0, stream>>>(x, y, stats, gamma, beta, out);
}

// Round 7
// 355.412 us; speedup vs baseline: 2.1157x; 1.9093x over previous
//
#include <hip/hip_runtime.h>
#include <cstdint>
#include <cstddef>

// Problem constants: N=4, C=D=256, H=W=64, L=4096
#define NB 4
#define CH 256
#define LL 4096

typedef unsigned short u16;
typedef unsigned int u32;
typedef __attribute__((ext_vector_type(8))) short bf16x8;
typedef __attribute__((ext_vector_type(4))) float f32x4;

#define GPTR(p) ((const __attribute__((address_space(1))) u32*)(p))
#define LPTR(p) ((__attribute__((address_space(3))) u32*)(p))

__device__ __forceinline__ float blo(u32 x) { return __uint_as_float(x << 16); }
__device__ __forceinline__ float bhi(u32 x) { return __uint_as_float(x & 0xffff0000u); }
__device__ __forceinline__ float b2f(u16 h) { return __uint_as_float(((u32)h) << 16); }
__device__ __forceinline__ u16 f2b(float f) {
    u32 u = __float_as_uint(f);
    u32 r = (u + 0x7fffu + ((u >> 16) & 1u)) >> 16;  // RNE
    return (u16)r;
}
__device__ __forceinline__ u32 pack2(float a, float b) {
    return (u32)f2b(a) | ((u32)f2b(b) << 16);
}

// ---------------------------------------------------------------------------
// Kernel 0: zero BN stats accumulators (512 floats)
// ---------------------------------------------------------------------------
__global__ void zero_stats(float* stats) { stats[threadIdx.x] = 0.0f; }

// ---------------------------------------------------------------------------
// Kernel 1: projections. out[d,l] = sum_c W[d,c] * x[n,c,l]
// grid (L/64, D/64, 12) where z = mat*4 + n ; mat 0=q, 1=k, 2=v
// q,k stored (N,L,D) bf16 ; vT stored (N,D,L) bf16  (MFMA fragment layouts)
// ---------------------------------------------------------------------------
__global__ __launch_bounds__(256) void proj_kernel(
    const float* __restrict__ x, const float* __restrict__ Wq,
    const float* __restrict__ Wk, const float* __restrict__ Wv,
    u16* __restrict__ q, u16* __restrict__ k, u16* __restrict__ vT) {
    const int n = blockIdx.z & 3;
    const int mat = blockIdx.z >> 2;
    const float* W = (mat == 0) ? Wq : ((mat == 1) ? Wk : Wv);
    const int l0 = blockIdx.x * 64;
    const int d0 = blockIdx.y * 64;
    const float* X = x + (size_t)n * CH * LL;

    __shared__ float Ws[16][68];
    __shared__ float Xs[16][68];

    const int tid = threadIdx.x;
    const int tx = tid & 15, ty = tid >> 4;

    float acc[4][4];
#pragma unroll
    for (int i = 0; i < 4; ++i)
#pragma unroll
        for (int j = 0; j < 4; ++j) acc[i][j] = 0.0f;

    for (int kt = 0; kt < 16; ++kt) {
        const int c0 = kt * 16;
#pragma unroll
        for (int i = 0; i < 4; ++i) {
            int e = tid + 256 * i;
            int cc = e & 15, dd = e >> 4;
            Ws[cc][dd] = W[(size_t)(d0 + dd) * CH + c0 + cc];
        }
#pragma unroll
        for (int i = 0; i < 4; ++i) {
            int e = tid + 256 * i;
            int ll = e & 63, cc = e >> 6;
            Xs[cc][ll] = X[(size_t)(c0 + cc) * LL + l0 + ll];
        }
        __syncthreads();
#pragma unroll
        for (int kk = 0; kk < 16; ++kk) {
            float a[4], b[4];
#pragma unroll
            for (int i = 0; i < 4; ++i) a[i] = Ws[kk][ty * 4 + i];
#pragma unroll
            for (int j = 0; j < 4; ++j) b[j] = Xs[kk][tx * 4 + j];
#pragma unroll
            for (int i = 0; i < 4; ++i)
#pragma unroll
                for (int j = 0; j < 4; ++j) acc[i][j] += a[i] * b[j];
        }
        __syncthreads();
    }

    if (mat == 2) {
        // vT[n][d][l]
        u16* o = vT + (size_t)n * CH * LL;
#pragma unroll
        for (int i = 0; i < 4; ++i) {
            u32 w0 = pack2(acc[i][0], acc[i][1]);
            u32 w1 = pack2(acc[i][2], acc[i][3]);
            *(uint2*)&o[(size_t)(d0 + ty * 4 + i) * LL + l0 + tx * 4] = make_uint2(w0, w1);
        }
    } else {
        // q or k: [n][l][d]
        u16* o = ((mat == 0) ? q : k) + (size_t)n * LL * CH;
#pragma unroll
        for (int j = 0; j < 4; ++j) {
            u32 w0 = pack2(acc[0][j], acc[1][j]);
            u32 w1 = pack2(acc[2][j], acc[3][j]);
            *(uint2*)&o[(size_t)(l0 + tx * 4 + j) * CH + d0 + ty * 4] = make_uint2(w0, w1);
        }
    }
}

// ---------------------------------------------------------------------------
// Kernel 2: flash attention, key-split. Block = 64 Q rows, 4 waves x 16 rows.
// blockIdx.z = key-split id; each split covers `iters`*32 keys.
// Staging via global_load_lds width=16 (no VGPR round-trip: R3-R6 showed the
// kb/vb register prefetch pushed live VGPRs to ~130 and the allocator spilled
// ~85 B/thread/iter to scratch at any launch-bounds setting -> 714-742 MB
// writes). Unpadded LDS tiles with XOR swizzle folded into the *global*
// address per lane (global_load_lds cannot scatter; padding is illegal):
//   K[32][256]:  chunk c of row r at position c^r          -> 2-way reads
//   V[256][32]:  chunk c of row d at c^((d&3)^((d>>2)&3))  -> 2-way reads
// No max-subtraction (scores/16 ~ N(0,1)): p = exp2(s*scale*log2e).
// Row-sum l accumulated in VALU, shuffle-reduced at the end.
// Writes un-normalized partial O (bf16) + l (fp32); merge kernel combines.
// LDS 38400 B: K 16K | V 16K | P[64][44] 5.5K  -> 4 blocks/CU
// ---------------------------------------------------------------------------
#define PSTRIDE 44
#define V_OFF 16384
#define P_OFF 32768

__global__ __launch_bounds__(256, 1) void fattn_kernel(
    const u16* __restrict__ q, const u16* __restrict__ k,
    const u16* __restrict__ vT, u16* __restrict__ Op, float* __restrict__ l_s,
    int iters) {
    const int n = blockIdx.y;
    const int s_id = blockIdx.z;
    const int l0 = blockIdx.x * 64;
    const int m_base = s_id * iters * 32;
    const int tid = threadIdx.x;
    const int w = tid >> 6;
    const int lane = tid & 63;
    const int lhi = lane >> 4, llo = lane & 15;

    __shared__ __align__(16) char smem[38400];
    u16* K_lds = (u16*)smem;            // [32][256], chunk-swizzled
    u16* V_lds = (u16*)(smem + V_OFF);  // [256][32], chunk-swizzled
    u16* P_lds = (u16*)(smem + P_OFF);  // [64][44]

    // ---- Q fragments (A-layout) direct from global ----
    bf16x8 qf[8];
    {
        const u16* base = q + (size_t)(n * LL + l0 + w * 16 + llo) * CH + lhi * 8;
#pragma unroll
        for (int ks = 0; ks < 8; ++ks) qf[ks] = *(const bf16x8*)(base + ks * 32);
    }

    const u16* kg = k + (size_t)n * LL * CH;
    const u16* vg = vT + (size_t)n * CH * LL;

    // per-instruction global offsets (iter-invariant); slot s = i*256 + tid
    int okK[4], okV[4];
#pragma unroll
    for (int i = 0; i < 4; ++i) {
        int s = i * 256 + tid;
        int rK = s >> 5;
        int cK = (s & 31) ^ rK;
        okK[i] = rK * CH + cK * 8;
        int dV = s >> 2;
        int cV = (s & 3) ^ ((dV & 3) ^ ((dV >> 2) & 3));
        okV[i] = dV * LL + cV * 8;
    }

    f32x4 oacc[16];
#pragma unroll
    for (int t = 0; t < 16; ++t) oacc[t] = (f32x4){0.f, 0.f, 0.f, 0.f};
    float lrun[4] = {0.f, 0.f, 0.f, 0.f};

    const float C1 = 0.09016844005556021f;  // (1/16) * log2(e)
    const int posV = (lhi ^ ((llo & 3) ^ (llo >> 2))) * 8;  // V read swizzle

    for (int it = 0; it < iters; ++it) {
        const int m0 = m_base + it * 32;
        const u16* kg2 = kg + (size_t)m0 * CH;
        const u16* vg2 = vg + m0;
        __syncthreads();  // previous tile's consumers done
#pragma unroll
        for (int i = 0; i < 4; ++i) {
            __builtin_amdgcn_global_load_lds(GPTR(kg2 + okK[i]),
                                             LPTR(K_lds + i * 2048 + w * 512),
                                             16, 0, 0);
            __builtin_amdgcn_global_load_lds(GPTR(vg2 + okV[i]),
                                             LPTR(V_lds + i * 2048 + w * 512),
                                             16, 0, 0);
        }
        __syncthreads();  // drains vmcnt (compiler emits waitcnt before barrier)

        // ---- S = Q·K^T : 2 col-tiles x 8 k-steps ----
        f32x4 s0 = (f32x4){0.f, 0.f, 0.f, 0.f};
        f32x4 s1 = (f32x4){0.f, 0.f, 0.f, 0.f};
#pragma unroll
        for (int ks = 0; ks < 8; ++ks) {
            const int cq = ks * 4 + lhi;
            bf16x8 b0 = *(const bf16x8*)(K_lds + llo * 256 + (cq ^ llo) * 8);
            bf16x8 b1 =
                *(const bf16x8*)(K_lds + (llo + 16) * 256 + (cq ^ (llo + 16)) * 8);
            s0 = __builtin_amdgcn_mfma_f32_16x16x32_bf16(qf[ks], b0, s0, 0, 0, 0);
            s1 = __builtin_amdgcn_mfma_f32_16x16x32_bf16(qf[ks], b1, s1, 0, 0, 0);
        }

        // ---- p = exp2(s * C1), write to P (bf16, [row][m]); lrun += p ----
        u16* pw = P_lds + (w * 16) * PSTRIDE;
#pragma unroll
        for (int r = 0; r < 4; ++r) {
            float p0 = __builtin_amdgcn_exp2f(s0[r] * C1);
            float p1 = __builtin_amdgcn_exp2f(s1[r] * C1);
            int lrow = lhi * 4 + r;
            pw[lrow * PSTRIDE + llo] = f2b(p0);
            pw[lrow * PSTRIDE + 16 + llo] = f2b(p1);
            lrun[r] += p0 + p1;
        }

        // ---- PV: A = P (wave-private rows, no barrier needed), B = V^T ----
        bf16x8 pf = *(const bf16x8*)(P_lds + (w * 16 + llo) * PSTRIDE + lhi * 8);
#pragma unroll
        for (int ct = 0; ct < 16; ++ct) {
            bf16x8 vf = *(const bf16x8*)(V_lds + (ct * 16 + llo) * 32 + posV);
            oacc[ct] = __builtin_amdgcn_mfma_f32_16x16x32_bf16(pf, vf, oacc[ct], 0, 0, 0);
        }
    }

    // ---- epilogue: store un-normalized partial O (bf16) + l (fp32) ----
    u16* ap = Op + (size_t)((s_id * NB + n) * (size_t)LL + l0 + w * 16) * CH;
    float* lp = l_s + (size_t)s_id * NB * LL + (size_t)n * LL + l0 + w * 16;
#pragma unroll
    for (int r = 0; r < 4; ++r) {
        // reduce lrun over the 16-lane llo group (row = w*16 + lhi*4 + r)
        float t = lrun[r];
        t += __shfl_xor(t, 1);
        t += __shfl_xor(t, 2);
        t += __shfl_xor(t, 4);
        t += __shfl_xor(t, 8);
        int lrow = lhi * 4 + r;
#pragma unroll
        for (int ct = 0; ct < 16; ++ct) {
            ap[(size_t)lrow * CH + ct * 16 + llo] = f2b(oacc[ct][r]);
        }
        if (llo == 0) lp[lrow] = t;
    }
}

// ---------------------------------------------------------------------------
// Kernel 2c: merge splits: att[i] = (sum_s Op[s][i]) / (sum_s l_s[s][row])
// one thread = 8 consecutive d's. invl computed inline (L2-hit loads).
// ---------------------------------------------------------------------------
__global__ __launch_bounds__(256) void merge_kernel(
    const u16* __restrict__ Op, const float* __restrict__ l_s,
    u16* __restrict__ att, int S) {
    const size_t t8 = (size_t)blockIdx.x * 256 + threadIdx.x;
    const size_t flat = t8 * 8;
    const size_t row = flat >> 8;
    float lsum = 0.0f;
    for (int s = 0; s < S; ++s) lsum += l_s[(size_t)s * NB * LL + row];
    const float inv = 1.0f / lsum;
    float acc[8];
#pragma unroll
    for (int j = 0; j < 8; ++j) acc[j] = 0.0f;
    for (int s = 0; s < S; ++s) {
        uint4 raw = *(const uint4*)(Op + (size_t)s * NB * LL * CH + flat);
        acc[0] += blo(raw.x); acc[1] += bhi(raw.x);
        acc[2] += blo(raw.y); acc[3] += bhi(raw.y);
        acc[4] += blo(raw.z); acc[5] += bhi(raw.z);
        acc[6] += blo(raw.w); acc[7] += bhi(raw.w);
    }
    uint4 o;
    o.x = pack2(acc[0] * inv, acc[1] * inv);
    o.y = pack2(acc[2] * inv, acc[3] * inv);
    o.z = pack2(acc[4] * inv, acc[5] * inv);
    o.w = pack2(acc[6] * inv, acc[7] * inv);
    *(uint4*)(att + flat) = o;
}

// ---------------------------------------------------------------------------
// Kernel 3: y[n,o,l] = sum_d Wo[o,d] * att[n,l,d] ; fused BN partial sums
// grid (L/64, C/64, N), 256 threads
// ---------------------------------------------------------------------------
__global__ __launch_bounds__(256) void out_kernel(
    const float* __restrict__ Wo, const u16* __restrict__ att,
    float* __restrict__ y, float* __restrict__ stats) {
    const int n = blockIdx.z;
    const int o0 = blockIdx.y * 64;
    const int l0 = blockIdx.x * 64;

    __shared__ float Wos[16][68];
    __shared__ float As[16][68];
    __shared__ float red[2][64][16];

    const int tid = threadIdx.x;
    const int tx = tid & 15, ty = tid >> 4;
    const u16* an = att + (size_t)n * LL * CH;

    float acc[4][4];
#pragma unroll
    for (int i = 0; i < 4; ++i)
#pragma unroll
        for (int j = 0; j < 4; ++j) acc[i][j] = 0.0f;

    for (int kt = 0; kt < 16; ++kt) {
        const int dk = kt * 16;
#pragma unroll
        for (int i = 0; i < 4; ++i) {
            int e = tid + 256 * i;
            int dd = e & 15, oo = e >> 4;
            Wos[dd][oo] = Wo[(size_t)(o0 + oo) * CH + dk + dd];
        }
#pragma unroll
        for (int i = 0; i < 4; ++i) {
            int e = tid + 256 * i;
            int dd = e & 15, ll = e >> 4;
            As[dd][ll] = b2f(an[(size_t)(l0 + ll) * CH + dk + dd]);
        }
        __syncthreads();
#pragma unroll
        for (int kk = 0; kk < 16; ++kk) {
            float a[4], b[4];
#pragma unroll
            for (int i = 0; i < 4; ++i) a[i] = Wos[kk][ty * 4 + i];
#pragma unroll
            for (int j = 0; j < 4; ++j) b[j] = As[kk][tx * 4 + j];
#pragma unroll
            for (int i = 0; i < 4; ++i)
#pragma unroll
                for (int j = 0; j < 4; ++j) acc[i][j] += a[i] * b[j];
        }
        __syncthreads();
    }

    float* yn = y + (size_t)n * CH * LL;
    float ts[4], tq[4];
#pragma unroll
    for (int i = 0; i < 4; ++i) { ts[i] = 0.0f; tq[i] = 0.0f; }
#pragma unroll
    for (int i = 0; i < 4; ++i) {
#pragma unroll
        for (int j = 0; j < 4; ++j) {
            float vv = acc[i][j];
            yn[(size_t)(o0 + ty * 4 + i) * LL + l0 + tx * 4 + j] = vv;
            ts[i] += vv;
            tq[i] += vv * vv;
        }
    }
#pragma unroll
    for (int i = 0; i < 4; ++i) {
        red[0][ty * 4 + i][tx] = ts[i];
        red[1][ty * 4 + i][tx] = tq[i];
    }
    __syncthreads();
    if (tid < 64) {
        float sa = 0.0f, qa = 0.0f;
#pragma unroll
        for (int t = 0; t < 16; ++t) { sa += red[0][tid][t]; qa += red[1][tid][t]; }
        atomicAdd(&stats[o0 + tid], sa);
        atomicAdd(&stats[256 + o0 + tid], qa);
    }
}

// ---------------------------------------------------------------------------
// Kernel 4: BN apply (batch stats, biased var) + residual. float4 streaming.
// ---------------------------------------------------------------------------
__global__ __launch_bounds__(256) void bn_kernel(
    const float* __restrict__ x, const float* __restrict__ y,
    const float* __restrict__ stats, const float* __restrict__ gamma,
    const float* __restrict__ beta, float* __restrict__ out) {
    const int idx = blockIdx.x * 256 + threadIdx.x;  // per float4
    const int base = idx * 4;
    const int c = (base >> 12) & 255;  // (base / L) % C
    const float cnt = 1.0f / 16384.0f; // N*L
    float mean = stats[c] * cnt;
    float var = stats[256 + c] * cnt - mean * mean;
    float rstd = rsqrtf(var + 1e-4f);
    float g = gamma[c] * rstd;
    float b = beta[c];
    float4 yv = ((const float4*)y)[idx];
    float4 xv = ((const float4*)x)[idx];
    float4 o;
    o.x = xv.x + (yv.x - mean) * g + b;
    o.y = xv.y + (yv.y - mean) * g + b;
    o.z = xv.z + (yv.z - mean) * g + b;
    o.w = xv.w + (yv.w - mean) * g + b;
    ((float4*)out)[idx] = o;
}

// ---------------------------------------------------------------------------
extern "C" void kernel_launch(void* const* d_in, const int* in_sizes, int n_in,
                              void* d_out, int out_size, void* d_ws, size_t ws_size,
                              hipStream_t stream) {
    const float* x = (const float*)d_in[0];
    const float* Wq = (const float*)d_in[1];
    const float* Wk = (const float*)d_in[2];
    const float* Wv = (const float*)d_in[3];
    const float* Wo = (const float*)d_in[4];
    const float* gamma = (const float*)d_in[5];
    const float* beta = (const float*)d_in[6];
    float* out = (float*)d_out;

    const size_t elems = (size_t)NB * LL * CH;  // 4,194,304

    // pick largest split count whose workspace fits
    int S = 1;
    for (int cand = 8; cand >= 2; cand >>= 1) {
        size_t need = elems * 2 * (size_t)(3 + cand) +
                      (size_t)cand * NB * LL * 4 + 4096;
        if (ws_size >= need) { S = cand; break; }
    }
    const int iters = 128 / S;

    char* wsb = (char*)d_ws;
    u16* q = (u16*)wsb;                          // 8.39 MB
    u16* k = q + elems;                          // 8.39 MB
    u16* vT = k + elems;                         // 8.39 MB
    u16* Op = vT + elems;                        // S * 8.39 MB
    float* l_s = (float*)(Op + (size_t)S * elems);        // S * 64 KB
    float* stats = l_s + (size_t)S * NB * LL;             // 2 KB
    u16* att = q;                                // reuse q (dead after fattn)
    float* y = (float*)k;                        // reuse k+vT (dead after merge)

    zero_stats<<<1, 512, 0, stream>>>(stats);
    proj_kernel<<<dim3(LL / 64, CH / 64, 12), 256, 0, stream>>>(x, Wq, Wk, Wv, q, k, vT);
    fattn_kernel<<<dim3(LL / 64, NB, S), 256, 0, stream>>>(q, k, vT, Op, l_s, iters);
    merge_kernel<<<(int)(elems / 8 / 256), 256, 0, stream>>>(Op, l_s, att, S);
    out_kernel<<<dim3(LL / 64, CH / 64, NB), 256, 0, stream>>>(Wo, att, y, stats);
    bn_kernel<<<(NB * CH * LL / 4) / 256, 256, 0, stream>>>(x, y, stats, gamma, beta, out);
}

// Round 8
// 318.904 us; speedup vs baseline: 2.3579x; 1.1145x over previous
//
#include <hip/hip_runtime.h>
#include <cstdint>
#include <cstddef>

// Problem constants: N=4, C=D=256, H=W=64, L=4096
#define NB 4
#define CH 256
#define LL 4096

typedef unsigned short u16;
typedef unsigned int u32;
typedef __attribute__((ext_vector_type(8))) short bf16x8;
typedef __attribute__((ext_vector_type(4))) float f32x4;

#define GPTR(p) ((const __attribute__((address_space(1))) u32*)(p))
#define LPTR(p) ((__attribute__((address_space(3))) u32*)(p))

__device__ __forceinline__ float blo(u32 x) { return __uint_as_float(x << 16); }
__device__ __forceinline__ float bhi(u32 x) { return __uint_as_float(x & 0xffff0000u); }
__device__ __forceinline__ float b2f(u16 h) { return __uint_as_float(((u32)h) << 16); }
__device__ __forceinline__ u16 f2b(float f) {
    u32 u = __float_as_uint(f);
    u32 r = (u + 0x7fffu + ((u >> 16) & 1u)) >> 16;  // RNE
    return (u16)r;
}
__device__ __forceinline__ u32 pack2(float a, float b) {
    return (u32)f2b(a) | ((u32)f2b(b) << 16);
}

// ---------------------------------------------------------------------------
// Kernel 0: zero BN stats accumulators (512 floats)
// ---------------------------------------------------------------------------
__global__ void zero_stats(float* stats) { stats[threadIdx.x] = 0.0f; }

// ---------------------------------------------------------------------------
// Kernel 0b: cast the four weight matrices to bf16. Wb[mat][d][c], mat
// 0=q,1=k,2=v,3=o. grid (64, 4), 256 thr, 4 elems/thr.
// ---------------------------------------------------------------------------
__global__ __launch_bounds__(256) void castw_kernel(
    const float* __restrict__ Wq, const float* __restrict__ Wk,
    const float* __restrict__ Wv, const float* __restrict__ Wo,
    u16* __restrict__ Wb) {
    const int i = blockIdx.x * 256 + threadIdx.x;
    const int m = blockIdx.y;
    const float* src = (m == 0) ? Wq : (m == 1) ? Wk : (m == 2) ? Wv : Wo;
    float4 v = ((const float4*)src)[i];
    uint2 o;
    o.x = pack2(v.x, v.y);
    o.y = pack2(v.z, v.w);
    ((uint2*)(Wb + m * 65536))[i] = o;
}

// ---------------------------------------------------------------------------
// Kernel 0c: transpose-cast x[n][c][l] f32 -> xT[n][l][c] bf16 (64x64 tiles).
// Makes the k(=c) dimension contiguous so all proj MFMA fragments are direct
// global reads (no LDS staging in the GEMMs themselves).
// ---------------------------------------------------------------------------
__global__ __launch_bounds__(256) void tcast_kernel(
    const float* __restrict__ x, u16* __restrict__ xT) {
    const int n = blockIdx.z;
    const int c0 = blockIdx.y * 64, l0 = blockIdx.x * 64;
    __shared__ u16 t[64][72];  // 72: keeps 16B-aligned rows (144 B)
    const float* xs = x + (size_t)n * CH * LL;
    const int tid = threadIdx.x;
    const int lq = (tid & 15) * 4, cc = tid >> 4;
#pragma unroll
    for (int p = 0; p < 4; ++p) {
        int c = cc + p * 16;
        float4 v = *(const float4*)&xs[(size_t)(c0 + c) * LL + l0 + lq];
        t[lq + 0][c] = f2b(v.x);
        t[lq + 1][c] = f2b(v.y);
        t[lq + 2][c] = f2b(v.z);
        t[lq + 3][c] = f2b(v.w);
    }
    __syncthreads();
    u16* xo = xT + (size_t)n * LL * CH;
    const int l = tid >> 2, c8 = (tid & 3) * 16;
#pragma unroll
    for (int h = 0; h < 2; ++h) {
        uint4 vv = *(uint4*)&t[l][c8 + h * 8];
        *(uint4*)&xo[(size_t)(l0 + l) * CH + c0 + c8 + h * 8] = vv;
    }
}

// ---------------------------------------------------------------------------
// Kernel 1a: q/k projections via MFMA. q[l][d] = sum_c xT[l][c] W[d][c].
// A = xT (row=l, k=c contiguous), B = W (col=d, k=c contiguous) -- both read
// DIRECTLY from global (L2/L3-hot); zero LDS. Wave = 16 l-rows x 128 d-cols.
// grid (L/64, dhalf*2+... y = dhalf | mat<<1, NB). Fragment patterns are the
// fattn-verified ones (A: base+ks*32; B: [col16+llo][lhi*8+ks*32]; D: fattn
// epilogue row/col).
// ---------------------------------------------------------------------------
__global__ __launch_bounds__(256, 1) void projqk_kernel(
    const u16* __restrict__ xT, const u16* __restrict__ Wb,
    u16* __restrict__ q, u16* __restrict__ k) {
    const int n = blockIdx.z;
    const int dhalf = blockIdx.y & 1, mat = blockIdx.y >> 1;
    const int l0 = blockIdx.x * 64;
    const int d0 = dhalf * 128;
    const int tid = threadIdx.x;
    const int w = tid >> 6, lane = tid & 63;
    const int lhi = lane >> 4, llo = lane & 15;

    const u16* xn = xT + (size_t)n * LL * CH;
    const u16* Wm = Wb + mat * 65536;

    bf16x8 af[8];
    const u16* abase = xn + (size_t)(l0 + w * 16 + llo) * CH + lhi * 8;
#pragma unroll
    for (int ks = 0; ks < 8; ++ks) af[ks] = *(const bf16x8*)(abase + ks * 32);

    f32x4 acc[8];
#pragma unroll
    for (int t = 0; t < 8; ++t) acc[t] = (f32x4){0.f, 0.f, 0.f, 0.f};

#pragma unroll
    for (int ks = 0; ks < 8; ++ks) {
#pragma unroll
        for (int ct = 0; ct < 8; ++ct) {
            bf16x8 bf = *(const bf16x8*)(Wm + (size_t)(d0 + ct * 16 + llo) * CH +
                                         ks * 32 + lhi * 8);
            acc[ct] = __builtin_amdgcn_mfma_f32_16x16x32_bf16(af[ks], bf, acc[ct], 0, 0, 0);
        }
    }

    u16* o = (mat ? k : q) + (size_t)n * LL * CH;
#pragma unroll
    for (int r = 0; r < 4; ++r) {
        int lr = l0 + w * 16 + lhi * 4 + r;
#pragma unroll
        for (int ct = 0; ct < 8; ++ct)
            o[(size_t)lr * CH + d0 + ct * 16 + llo] = f2b(acc[ct][r]);
    }
}

// ---------------------------------------------------------------------------
// Kernel 1b: v projection, transposed output. vT[d][l] = sum_c W[d][c] xT[l][c].
// A = Wv (row=d), B = xT (col=l). Wave = 16 d-rows x 128 l-cols.
// grid (L/128, CH/64, NB).
// ---------------------------------------------------------------------------
__global__ __launch_bounds__(256, 1) void projv_kernel(
    const u16* __restrict__ xT, const u16* __restrict__ Wb,
    u16* __restrict__ vT) {
    const int n = blockIdx.z;
    const int d0 = blockIdx.y * 64;
    const int l0 = blockIdx.x * 128;
    const int tid = threadIdx.x;
    const int w = tid >> 6, lane = tid & 63;
    const int lhi = lane >> 4, llo = lane & 15;

    const u16* xn = xT + (size_t)n * LL * CH;
    const u16* Wm = Wb + 2 * 65536;

    bf16x8 af[8];
    const u16* abase = Wm + (size_t)(d0 + w * 16 + llo) * CH + lhi * 8;
#pragma unroll
    for (int ks = 0; ks < 8; ++ks) af[ks] = *(const bf16x8*)(abase + ks * 32);

    f32x4 acc[8];
#pragma unroll
    for (int t = 0; t < 8; ++t) acc[t] = (f32x4){0.f, 0.f, 0.f, 0.f};

#pragma unroll
    for (int ks = 0; ks < 8; ++ks) {
#pragma unroll
        for (int ct = 0; ct < 8; ++ct) {
            bf16x8 bf = *(const bf16x8*)(xn + (size_t)(l0 + ct * 16 + llo) * CH +
                                         ks * 32 + lhi * 8);
            acc[ct] = __builtin_amdgcn_mfma_f32_16x16x32_bf16(af[ks], bf, acc[ct], 0, 0, 0);
        }
    }

    u16* o = vT + (size_t)n * CH * LL;
#pragma unroll
    for (int r = 0; r < 4; ++r) {
        int dr = d0 + w * 16 + lhi * 4 + r;
#pragma unroll
        for (int ct = 0; ct < 8; ++ct)
            o[(size_t)dr * LL + l0 + ct * 16 + llo] = f2b(acc[ct][r]);
    }
}

// ---------------------------------------------------------------------------
// Kernel 2: flash attention (UNCHANGED from R7 -- 144 us, spill-free).
// ---------------------------------------------------------------------------
#define PSTRIDE 44
#define V_OFF 16384
#define P_OFF 32768

__global__ __launch_bounds__(256, 1) void fattn_kernel(
    const u16* __restrict__ q, const u16* __restrict__ k,
    const u16* __restrict__ vT, u16* __restrict__ Op, float* __restrict__ l_s,
    int iters) {
    const int n = blockIdx.y;
    const int s_id = blockIdx.z;
    const int l0 = blockIdx.x * 64;
    const int m_base = s_id * iters * 32;
    const int tid = threadIdx.x;
    const int w = tid >> 6;
    const int lane = tid & 63;
    const int lhi = lane >> 4, llo = lane & 15;

    __shared__ __align__(16) char smem[38400];
    u16* K_lds = (u16*)smem;            // [32][256], chunk-swizzled
    u16* V_lds = (u16*)(smem + V_OFF);  // [256][32], chunk-swizzled
    u16* P_lds = (u16*)(smem + P_OFF);  // [64][44]

    bf16x8 qf[8];
    {
        const u16* base = q + (size_t)(n * LL + l0 + w * 16 + llo) * CH + lhi * 8;
#pragma unroll
        for (int ks = 0; ks < 8; ++ks) qf[ks] = *(const bf16x8*)(base + ks * 32);
    }

    const u16* kg = k + (size_t)n * LL * CH;
    const u16* vg = vT + (size_t)n * CH * LL;

    int okK[4], okV[4];
#pragma unroll
    for (int i = 0; i < 4; ++i) {
        int s = i * 256 + tid;
        int rK = s >> 5;
        int cK = (s & 31) ^ rK;
        okK[i] = rK * CH + cK * 8;
        int dV = s >> 2;
        int cV = (s & 3) ^ ((dV & 3) ^ ((dV >> 2) & 3));
        okV[i] = dV * LL + cV * 8;
    }

    f32x4 oacc[16];
#pragma unroll
    for (int t = 0; t < 16; ++t) oacc[t] = (f32x4){0.f, 0.f, 0.f, 0.f};
    float lrun[4] = {0.f, 0.f, 0.f, 0.f};

    const float C1 = 0.09016844005556021f;  // (1/16) * log2(e)
    const int posV = (lhi ^ ((llo & 3) ^ (llo >> 2))) * 8;

    for (int it = 0; it < iters; ++it) {
        const int m0 = m_base + it * 32;
        const u16* kg2 = kg + (size_t)m0 * CH;
        const u16* vg2 = vg + m0;
        __syncthreads();
#pragma unroll
        for (int i = 0; i < 4; ++i) {
            __builtin_amdgcn_global_load_lds(GPTR(kg2 + okK[i]),
                                             LPTR(K_lds + i * 2048 + w * 512),
                                             16, 0, 0);
            __builtin_amdgcn_global_load_lds(GPTR(vg2 + okV[i]),
                                             LPTR(V_lds + i * 2048 + w * 512),
                                             16, 0, 0);
        }
        __syncthreads();

        f32x4 s0 = (f32x4){0.f, 0.f, 0.f, 0.f};
        f32x4 s1 = (f32x4){0.f, 0.f, 0.f, 0.f};
#pragma unroll
        for (int ks = 0; ks < 8; ++ks) {
            const int cq = ks * 4 + lhi;
            bf16x8 b0 = *(const bf16x8*)(K_lds + llo * 256 + (cq ^ llo) * 8);
            bf16x8 b1 =
                *(const bf16x8*)(K_lds + (llo + 16) * 256 + (cq ^ (llo + 16)) * 8);
            s0 = __builtin_amdgcn_mfma_f32_16x16x32_bf16(qf[ks], b0, s0, 0, 0, 0);
            s1 = __builtin_amdgcn_mfma_f32_16x16x32_bf16(qf[ks], b1, s1, 0, 0, 0);
        }

        u16* pw = P_lds + (w * 16) * PSTRIDE;
#pragma unroll
        for (int r = 0; r < 4; ++r) {
            float p0 = __builtin_amdgcn_exp2f(s0[r] * C1);
            float p1 = __builtin_amdgcn_exp2f(s1[r] * C1);
            int lrow = lhi * 4 + r;
            pw[lrow * PSTRIDE + llo] = f2b(p0);
            pw[lrow * PSTRIDE + 16 + llo] = f2b(p1);
            lrun[r] += p0 + p1;
        }

        bf16x8 pf = *(const bf16x8*)(P_lds + (w * 16 + llo) * PSTRIDE + lhi * 8);
#pragma unroll
        for (int ct = 0; ct < 16; ++ct) {
            bf16x8 vf = *(const bf16x8*)(V_lds + (ct * 16 + llo) * 32 + posV);
            oacc[ct] = __builtin_amdgcn_mfma_f32_16x16x32_bf16(pf, vf, oacc[ct], 0, 0, 0);
        }
    }

    u16* ap = Op + (size_t)((s_id * NB + n) * (size_t)LL + l0 + w * 16) * CH;
    float* lp = l_s + (size_t)s_id * NB * LL + (size_t)n * LL + l0 + w * 16;
#pragma unroll
    for (int r = 0; r < 4; ++r) {
        float t = lrun[r];
        t += __shfl_xor(t, 1);
        t += __shfl_xor(t, 2);
        t += __shfl_xor(t, 4);
        t += __shfl_xor(t, 8);
        int lrow = lhi * 4 + r;
#pragma unroll
        for (int ct = 0; ct < 16; ++ct) {
            ap[(size_t)lrow * CH + ct * 16 + llo] = f2b(oacc[ct][r]);
        }
        if (llo == 0) lp[lrow] = t;
    }
}

// ---------------------------------------------------------------------------
// Kernel 2c: merge splits: att[i] = (sum_s Op[s][i]) / (sum_s l_s[s][row])
// ---------------------------------------------------------------------------
__global__ __launch_bounds__(256) void merge_kernel(
    const u16* __restrict__ Op, const float* __restrict__ l_s,
    u16* __restrict__ att, int S) {
    const size_t t8 = (size_t)blockIdx.x * 256 + threadIdx.x;
    const size_t flat = t8 * 8;
    const size_t row = flat >> 8;
    float lsum = 0.0f;
    for (int s = 0; s < S; ++s) lsum += l_s[(size_t)s * NB * LL + row];
    const float inv = 1.0f / lsum;
    float acc[8];
#pragma unroll
    for (int j = 0; j < 8; ++j) acc[j] = 0.0f;
    for (int s = 0; s < S; ++s) {
        uint4 raw = *(const uint4*)(Op + (size_t)s * NB * LL * CH + flat);
        acc[0] += blo(raw.x); acc[1] += bhi(raw.x);
        acc[2] += blo(raw.y); acc[3] += bhi(raw.y);
        acc[4] += blo(raw.z); acc[5] += bhi(raw.z);
        acc[6] += blo(raw.w); acc[7] += bhi(raw.w);
    }
    uint4 o;
    o.x = pack2(acc[0] * inv, acc[1] * inv);
    o.y = pack2(acc[2] * inv, acc[3] * inv);
    o.z = pack2(acc[4] * inv, acc[5] * inv);
    o.w = pack2(acc[6] * inv, acc[7] * inv);
    *(uint4*)(att + flat) = o;
}

// ---------------------------------------------------------------------------
// Kernel 3: output projection via MFMA + fused BN partial sums.
// y[n][o][l] = sum_d Wo[o][d] att[n][l][d].  A = Wo (row=o, k=d contiguous),
// B = att (col=l, k=d contiguous) -- direct global reads, zero LDS staging.
// Wave = 16 o-rows x 128 l-cols. grid (L/128, CH/64, NB).
// ---------------------------------------------------------------------------
__global__ __launch_bounds__(256, 1) void outm_kernel(
    const u16* __restrict__ Wb, const u16* __restrict__ att,
    float* __restrict__ y, float* __restrict__ stats) {
    const int n = blockIdx.z;
    const int o0 = blockIdx.y * 64;
    const int l0 = blockIdx.x * 128;
    const int tid = threadIdx.x;
    const int w = tid >> 6, lane = tid & 63;
    const int lhi = lane >> 4, llo = lane & 15;

    const u16* an = att + (size_t)n * LL * CH;
    const u16* Wm = Wb + 3 * 65536;

    bf16x8 af[8];
    const u16* abase = Wm + (size_t)(o0 + w * 16 + llo) * CH + lhi * 8;
#pragma unroll
    for (int ks = 0; ks < 8; ++ks) af[ks] = *(const bf16x8*)(abase + ks * 32);

    f32x4 acc[8];
#pragma unroll
    for (int t = 0; t < 8; ++t) acc[t] = (f32x4){0.f, 0.f, 0.f, 0.f};

#pragma unroll
    for (int ks = 0; ks < 8; ++ks) {
#pragma unroll
        for (int ct = 0; ct < 8; ++ct) {
            bf16x8 bf = *(const bf16x8*)(an + (size_t)(l0 + ct * 16 + llo) * CH +
                                         ks * 32 + lhi * 8);
            acc[ct] = __builtin_amdgcn_mfma_f32_16x16x32_bf16(af[ks], bf, acc[ct], 0, 0, 0);
        }
    }

    float* yn = y + (size_t)n * CH * LL;
#pragma unroll
    for (int r = 0; r < 4; ++r) {
        const int orow = o0 + w * 16 + lhi * 4 + r;
        float ts = 0.0f, tq = 0.0f;
#pragma unroll
        for (int ct = 0; ct < 8; ++ct) {
            float vv = acc[ct][r];
            yn[(size_t)orow * LL + l0 + ct * 16 + llo] = vv;
            ts += vv;
            tq += vv * vv;
        }
        // reduce over the 16-lane llo group -> full 128-l partial for orow
        ts += __shfl_xor(ts, 1); tq += __shfl_xor(tq, 1);
        ts += __shfl_xor(ts, 2); tq += __shfl_xor(tq, 2);
        ts += __shfl_xor(ts, 4); tq += __shfl_xor(tq, 4);
        ts += __shfl_xor(ts, 8); tq += __shfl_xor(tq, 8);
        if (llo == 0) {
            atomicAdd(&stats[orow], ts);
            atomicAdd(&stats[256 + orow], tq);
        }
    }
}

// ---------------------------------------------------------------------------
// Kernel 4: BN apply (batch stats, biased var) + residual. float4 streaming.
// ---------------------------------------------------------------------------
__global__ __launch_bounds__(256) void bn_kernel(
    const float* __restrict__ x, const float* __restrict__ y,
    const float* __restrict__ stats, const float* __restrict__ gamma,
    const float* __restrict__ beta, float* __restrict__ out) {
    const int idx = blockIdx.x * 256 + threadIdx.x;  // per float4
    const int base = idx * 4;
    const int c = (base >> 12) & 255;  // (base / L) % C
    const float cnt = 1.0f / 16384.0f; // N*L
    float mean = stats[c] * cnt;
    float var = stats[256 + c] * cnt - mean * mean;
    float rstd = rsqrtf(var + 1e-4f);
    float g = gamma[c] * rstd;
    float b = beta[c];
    float4 yv = ((const float4*)y)[idx];
    float4 xv = ((const float4*)x)[idx];
    float4 o;
    o.x = xv.x + (yv.x - mean) * g + b;
    o.y = xv.y + (yv.y - mean) * g + b;
    o.z = xv.z + (yv.z - mean) * g + b;
    o.w = xv.w + (yv.w - mean) * g + b;
    ((float4*)out)[idx] = o;
}

// ---------------------------------------------------------------------------
extern "C" void kernel_launch(void* const* d_in, const int* in_sizes, int n_in,
                              void* d_out, int out_size, void* d_ws, size_t ws_size,
                              hipStream_t stream) {
    const float* x = (const float*)d_in[0];
    const float* Wq = (const float*)d_in[1];
    const float* Wk = (const float*)d_in[2];
    const float* Wv = (const float*)d_in[3];
    const float* Wo = (const float*)d_in[4];
    const float* gamma = (const float*)d_in[5];
    const float* beta = (const float*)d_in[6];
    float* out = (float*)d_out;

    const size_t elems = (size_t)NB * LL * CH;  // 4,194,304

    // pick largest split count whose workspace fits
    int S = 1;
    for (int cand = 8; cand >= 2; cand >>= 1) {
        size_t need = elems * 2 * (size_t)(3 + cand) +
                      (size_t)cand * NB * LL * 4 + 4 * 65536 * 2 + 8192;
        if (ws_size >= need) { S = cand; break; }
    }
    const int iters = 128 / S;

    char* wsb = (char*)d_ws;
    u16* q = (u16*)wsb;                          // 8.39 MB
    u16* k = q + elems;                          // 8.39 MB
    u16* vT = k + elems;                         // 8.39 MB
    u16* Op = vT + elems;                        // S * 8.39 MB
    u16* xT = Op;                                // overlay: dead before fattn
    float* l_s = (float*)(Op + (size_t)S * elems);        // S * 64 KB
    u16* Wb = (u16*)(l_s + (size_t)S * NB * LL);          // 512 KB
    float* stats = (float*)(Wb + 4 * 65536);              // 2 KB
    u16* att = q;                                // reuse q (dead after fattn)
    float* y = (float*)k;                        // reuse k+vT (dead after merge)

    zero_stats<<<1, 512, 0, stream>>>(stats);
    castw_kernel<<<dim3(64, 4), 256, 0, stream>>>(Wq, Wk, Wv, Wo, Wb);
    tcast_kernel<<<dim3(LL / 64, CH / 64, NB), 256, 0, stream>>>(x, xT);
    projqk_kernel<<<dim3(LL / 64, 4, NB), 256, 0, stream>>>(xT, Wb, q, k);
    projv_kernel<<<dim3(LL / 128, CH / 64, NB), 256, 0, stream>>>(xT, Wb, vT);
    fattn_kernel<<<dim3(LL / 64, NB, S), 256, 0, stream>>>(q, k, vT, Op, l_s, iters);
    merge_kernel<<<(int)(elems / 8 / 256), 256, 0, stream>>>(Op, l_s, att, S);
    outm_kernel<<<dim3(LL / 128, CH / 64, NB), 256, 0, stream>>>(Wb, att, y, stats);
    bn_kernel<<<(NB * CH * LL / 4) / 256, 256, 0, stream>>>(x, y, stats, gamma, beta, out);
}

// Round 10
// 316.243 us; speedup vs baseline: 2.3777x; 1.0084x over previous
//
#include <hip/hip_runtime.h>
#include <cstdint>
#include <cstddef>

// Problem constants: N=4, C=D=256, H=W=64, L=4096
#define NB 4
#define CH 256
#define LL 4096

typedef unsigned short u16;
typedef unsigned int u32;
typedef unsigned char u8;
typedef long long i64;
typedef __attribute__((ext_vector_type(8))) short bf16x8;
typedef __attribute__((ext_vector_type(4))) float f32x4;

#define GPTR(p) ((const __attribute__((address_space(1))) u32*)(p))
#define LPTR(p) ((__attribute__((address_space(3))) u32*)(p))

__device__ __forceinline__ float blo(u32 x) { return __uint_as_float(x << 16); }
__device__ __forceinline__ float bhi(u32 x) { return __uint_as_float(x & 0xffff0000u); }
__device__ __forceinline__ float b2f(u16 h) { return __uint_as_float(((u32)h) << 16); }
__device__ __forceinline__ u16 f2b(float f) {
    u32 u = __float_as_uint(f);
    u32 r = (u + 0x7fffu + ((u >> 16) & 1u)) >> 16;  // RNE
    return (u16)r;
}
__device__ __forceinline__ u32 pack2(float a, float b) {
    return (u32)f2b(a) | ((u32)f2b(b) << 16);
}
__device__ __forceinline__ u8 f2fp8(float a) {
    return (u8)(__builtin_amdgcn_cvt_pk_fp8_f32(a, a, 0, false) & 0xff);
}

// ---------------------------------------------------------------------------
// Kernel 0b: cast weights to bf16 (Wb[mat][d][c]) + zero BN stats.
// ---------------------------------------------------------------------------
__global__ __launch_bounds__(256) void castw_kernel(
    const float* __restrict__ Wq, const float* __restrict__ Wk,
    const float* __restrict__ Wv, const float* __restrict__ Wo,
    u16* __restrict__ Wb, float* __restrict__ stats) {
    const int i = blockIdx.x * 256 + threadIdx.x;
    const int m = blockIdx.y;
    if (m == 0 && blockIdx.x < 2) stats[i] = 0.0f;
    const float* src = (m == 0) ? Wq : (m == 1) ? Wk : (m == 2) ? Wv : Wo;
    float4 v = ((const float4*)src)[i];
    uint2 o;
    o.x = pack2(v.x, v.y);
    o.y = pack2(v.z, v.w);
    ((uint2*)(Wb + m * 65536))[i] = o;
}

// ---------------------------------------------------------------------------
// Kernel 0c: transpose-cast x[n][c][l] f32 -> xT[n][l][c] bf16 (64x64 tiles).
// ---------------------------------------------------------------------------
__global__ __launch_bounds__(256) void tcast_kernel(
    const float* __restrict__ x, u16* __restrict__ xT) {
    const int n = blockIdx.z;
    const int c0 = blockIdx.y * 64, l0 = blockIdx.x * 64;
    __shared__ u16 t[64][72];
    const float* xs = x + (size_t)n * CH * LL;
    const int tid = threadIdx.x;
    const int lq = (tid & 15) * 4, cc = tid >> 4;
#pragma unroll
    for (int p = 0; p < 4; ++p) {
        int c = cc + p * 16;
        float4 v = *(const float4*)&xs[(size_t)(c0 + c) * LL + l0 + lq];
        t[lq + 0][c] = f2b(v.x);
        t[lq + 1][c] = f2b(v.y);
        t[lq + 2][c] = f2b(v.z);
        t[lq + 3][c] = f2b(v.w);
    }
    __syncthreads();
    u16* xo = xT + (size_t)n * LL * CH;
    const int l = tid >> 2, c8 = (tid & 3) * 16;
#pragma unroll
    for (int h = 0; h < 2; ++h) {
        uint4 vv = *(uint4*)&t[l][c8 + h * 8];
        *(uint4*)&xo[(size_t)(l0 + l) * CH + c0 + c8 + h * 8] = vv;
    }
}

// ---------------------------------------------------------------------------
// Kernel 1a: q/k projections via bf16 MFMA, output bf16 (correlated query-
// side quantization error must stay bf16 -- R9's fp8 q/k gave absmax 0.22).
// ---------------------------------------------------------------------------
__global__ __launch_bounds__(256, 1) void projqk_kernel(
    const u16* __restrict__ xT, const u16* __restrict__ Wb,
    u16* __restrict__ q, u16* __restrict__ k) {
    const int n = blockIdx.z;
    const int dhalf = blockIdx.y & 1, mat = blockIdx.y >> 1;
    const int l0 = blockIdx.x * 64;
    const int d0 = dhalf * 128;
    const int tid = threadIdx.x;
    const int w = tid >> 6, lane = tid & 63;
    const int lhi = lane >> 4, llo = lane & 15;

    const u16* xn = xT + (size_t)n * LL * CH;
    const u16* Wm = Wb + mat * 65536;

    bf16x8 af[8];
    const u16* abase = xn + (size_t)(l0 + w * 16 + llo) * CH + lhi * 8;
#pragma unroll
    for (int ks = 0; ks < 8; ++ks) af[ks] = *(const bf16x8*)(abase + ks * 32);

    f32x4 acc[8];
#pragma unroll
    for (int t = 0; t < 8; ++t) acc[t] = (f32x4){0.f, 0.f, 0.f, 0.f};

#pragma unroll
    for (int ks = 0; ks < 8; ++ks) {
#pragma unroll
        for (int ct = 0; ct < 8; ++ct) {
            bf16x8 bf = *(const bf16x8*)(Wm + (size_t)(d0 + ct * 16 + llo) * CH +
                                         ks * 32 + lhi * 8);
            acc[ct] = __builtin_amdgcn_mfma_f32_16x16x32_bf16(af[ks], bf, acc[ct], 0, 0, 0);
        }
    }

    u16* o = (mat ? k : q) + (size_t)n * LL * CH;
#pragma unroll
    for (int r = 0; r < 4; ++r) {
        int lr = l0 + w * 16 + lhi * 4 + r;
#pragma unroll
        for (int ct = 0; ct < 8; ++ct)
            o[(size_t)lr * CH + d0 + ct * 16 + llo] = f2b(acc[ct][r]);
    }
}

// ---------------------------------------------------------------------------
// Kernel 1b: v projection -> v8T[n][d][l] fp8 (V-side errors average across
// keys -- safe in fp8). A = Wv, B = xT.
// ---------------------------------------------------------------------------
__global__ __launch_bounds__(256, 1) void projv_kernel(
    const u16* __restrict__ xT, const u16* __restrict__ Wb,
    u8* __restrict__ v8T) {
    const int n = blockIdx.z;
    const int d0 = blockIdx.y * 64;
    const int l0 = blockIdx.x * 128;
    const int tid = threadIdx.x;
    const int w = tid >> 6, lane = tid & 63;
    const int lhi = lane >> 4, llo = lane & 15;

    const u16* xn = xT + (size_t)n * LL * CH;
    const u16* Wm = Wb + 2 * 65536;

    bf16x8 af[8];
    const u16* abase = Wm + (size_t)(d0 + w * 16 + llo) * CH + lhi * 8;
#pragma unroll
    for (int ks = 0; ks < 8; ++ks) af[ks] = *(const bf16x8*)(abase + ks * 32);

    f32x4 acc[8];
#pragma unroll
    for (int t = 0; t < 8; ++t) acc[t] = (f32x4){0.f, 0.f, 0.f, 0.f};

#pragma unroll
    for (int ks = 0; ks < 8; ++ks) {
#pragma unroll
        for (int ct = 0; ct < 8; ++ct) {
            bf16x8 bf = *(const bf16x8*)(xn + (size_t)(l0 + ct * 16 + llo) * CH +
                                         ks * 32 + lhi * 8);
            acc[ct] = __builtin_amdgcn_mfma_f32_16x16x32_bf16(af[ks], bf, acc[ct], 0, 0, 0);
        }
    }

    u8* o = v8T + (size_t)n * CH * LL;
#pragma unroll
    for (int r = 0; r < 4; ++r) {
        int dr = d0 + w * 16 + lhi * 4 + r;
#pragma unroll
        for (int ct = 0; ct < 8; ++ct)
            o[(size_t)dr * LL + l0 + ct * 16 + llo] = f2fp8(acc[ct][r]);
    }
}

// ---------------------------------------------------------------------------
// Kernel 2: HYBRID flash attention. QK^T in bf16 (R7/R8-verified code);
// P·V in fp8 (R9-verified layout -- its 0.22 absmax was pure quantization,
// correlated Q/K-side; P/V errors average across keys). Key-split.
// LDS 27136 B: K[32][256]bf16 16K | V[256][32]fp8 8K | P[64][40]fp8 2.5K
// K swizzle (u16 chunks of 8): chunk c of row r at c^r (R7).
// V swizzle (byte chunks of 16): chunk c of row d at c^(d&1) (R9).
// ---------------------------------------------------------------------------
#define V_OFF 16384
#define P_OFF 24576

__global__ __launch_bounds__(256, 1) void fattn_kernel(
    const u16* __restrict__ q, const u16* __restrict__ k,
    const u8* __restrict__ v8T, u16* __restrict__ Op, float* __restrict__ l_s,
    int iters) {
    const int n = blockIdx.y;
    const int s_id = blockIdx.z;
    const int l0 = blockIdx.x * 64;
    const int m_base = s_id * iters * 32;
    const int tid = threadIdx.x;
    const int w = tid >> 6;
    const int lane = tid & 63;
    const int lhi = lane >> 4, llo = lane & 15;

    __shared__ __align__(16) char smem[27136];
    u16* K_lds = (u16*)smem;       // [32][256] u16, chunk-swizzled
    char* V_lds = smem + V_OFF;    // [256][32] B fp8, chunk-swizzled
    char* P_lds = smem + P_OFF;    // [64][40] B fp8

    // ---- Q fragments (A-layout, bf16) direct from global ----
    bf16x8 qf[8];
    {
        const u16* base = q + (size_t)(n * LL + l0 + w * 16 + llo) * CH + lhi * 8;
#pragma unroll
        for (int ks = 0; ks < 8; ++ks) qf[ks] = *(const bf16x8*)(base + ks * 32);
    }

    const u16* kg = k + (size_t)n * LL * CH;
    const u8* vg = v8T + (size_t)n * CH * LL;

    // iter-invariant global offsets. K: 1024 16B-chunks (u16 elem offsets);
    // V: 512 16B-chunks (byte offsets).
    int okK[4], okV[2];
#pragma unroll
    for (int i = 0; i < 4; ++i) {
        int s = i * 256 + tid;
        int rK = s >> 5;
        int cK = (s & 31) ^ rK;
        okK[i] = rK * CH + cK * 8;
    }
#pragma unroll
    for (int i = 0; i < 2; ++i) {
        int s = i * 256 + tid;
        int dV = s >> 1;
        int cV = (s & 1) ^ (dV & 1);
        okV[i] = dV * LL + cV * 16;
    }

    f32x4 oacc[16];
#pragma unroll
    for (int t = 0; t < 16; ++t) oacc[t] = (f32x4){0.f, 0.f, 0.f, 0.f};
    float lrun[4] = {0.f, 0.f, 0.f, 0.f};

    const float C1 = 0.09016844005556021f;  // (1/16) * log2(e)

    for (int it = 0; it < iters; ++it) {
        const int m0 = m_base + it * 32;
        const u16* kg2 = kg + (size_t)m0 * CH;
        const u8* vg2 = vg + m0;
        __syncthreads();  // previous tile's consumers done
#pragma unroll
        for (int i = 0; i < 4; ++i) {
            __builtin_amdgcn_global_load_lds(GPTR(kg2 + okK[i]),
                                             LPTR(K_lds + i * 2048 + w * 512),
                                             16, 0, 0);
        }
#pragma unroll
        for (int i = 0; i < 2; ++i) {
            __builtin_amdgcn_global_load_lds(GPTR(vg2 + okV[i]),
                                             LPTR(V_lds + i * 4096 + w * 1024),
                                             16, 0, 0);
        }
        __syncthreads();  // drain (compiler emits vmcnt(0) before barrier)

        // ---- S = Q·K^T : bf16, 2 col-tiles x 8 k-steps ----
        f32x4 s0 = (f32x4){0.f, 0.f, 0.f, 0.f};
        f32x4 s1 = (f32x4){0.f, 0.f, 0.f, 0.f};
#pragma unroll
        for (int ks = 0; ks < 8; ++ks) {
            const int cq = ks * 4 + lhi;
            bf16x8 b0 = *(const bf16x8*)(K_lds + llo * 256 + (cq ^ llo) * 8);
            bf16x8 b1 =
                *(const bf16x8*)(K_lds + (llo + 16) * 256 + (cq ^ (llo + 16)) * 8);
            s0 = __builtin_amdgcn_mfma_f32_16x16x32_bf16(qf[ks], b0, s0, 0, 0, 0);
            s1 = __builtin_amdgcn_mfma_f32_16x16x32_bf16(qf[ks], b1, s1, 0, 0, 0);
        }

        // ---- p = exp2(s*C1) (f32), store fp8 to P; lrun += p ----
        char* pw = P_lds + (w * 16) * 40;
#pragma unroll
        for (int r = 0; r < 4; ++r) {
            float p0 = __builtin_amdgcn_exp2f(s0[r] * C1);
            float p1 = __builtin_amdgcn_exp2f(s1[r] * C1);
            u32 pk = (u32)__builtin_amdgcn_cvt_pk_fp8_f32(p0, p1, 0, false);
            int lrow = lhi * 4 + r;
            pw[lrow * 40 + llo] = (char)(pk & 0xff);
            pw[lrow * 40 + 16 + llo] = (char)((pk >> 8) & 0xff);
            lrun[r] += p0 + p1;
        }

        // ---- PV: fp8. A = P (wave-private rows), B = V^T fragments ----
        i64 pf = *(const i64*)(P_lds + (w * 16 + llo) * 40 + lhi * 8);
#pragma unroll
        for (int ct = 0; ct < 16; ++ct) {
            const int d = ct * 16 + llo;
            i64 vf = *(const i64*)(V_lds + d * 32 + ((((lhi >> 1) ^ (d & 1))) << 4) +
                                   (lhi & 1) * 8);
            oacc[ct] = __builtin_amdgcn_mfma_f32_16x16x32_fp8_fp8(pf, vf, oacc[ct], 0, 0, 0);
        }
    }

    // ---- epilogue: store un-normalized partial O (bf16) + l (fp32) ----
    u16* ap = Op + (size_t)((s_id * NB + n) * (size_t)LL + l0 + w * 16) * CH;
    float* lp = l_s + (size_t)s_id * NB * LL + (size_t)n * LL + l0 + w * 16;
#pragma unroll
    for (int r = 0; r < 4; ++r) {
        float t = lrun[r];
        t += __shfl_xor(t, 1);
        t += __shfl_xor(t, 2);
        t += __shfl_xor(t, 4);
        t += __shfl_xor(t, 8);
        int lrow = lhi * 4 + r;
#pragma unroll
        for (int ct = 0; ct < 16; ++ct) {
            ap[(size_t)lrow * CH + ct * 16 + llo] = f2b(oacc[ct][r]);
        }
        if (llo == 0) lp[lrow] = t;
    }
}

// ---------------------------------------------------------------------------
// Kernel 2c: merge splits: att[i] = (sum_s Op[s][i]) / (sum_s l_s[s][row])
// ---------------------------------------------------------------------------
__global__ __launch_bounds__(256) void merge_kernel(
    const u16* __restrict__ Op, const float* __restrict__ l_s,
    u16* __restrict__ att, int S) {
    const size_t t8 = (size_t)blockIdx.x * 256 + threadIdx.x;
    const size_t flat = t8 * 8;
    const size_t row = flat >> 8;
    float lsum = 0.0f;
    for (int s = 0; s < S; ++s) lsum += l_s[(size_t)s * NB * LL + row];
    const float inv = 1.0f / lsum;
    float acc[8];
#pragma unroll
    for (int j = 0; j < 8; ++j) acc[j] = 0.0f;
    for (int s = 0; s < S; ++s) {
        uint4 raw = *(const uint4*)(Op + (size_t)s * NB * LL * CH + flat);
        acc[0] += blo(raw.x); acc[1] += bhi(raw.x);
        acc[2] += blo(raw.y); acc[3] += bhi(raw.y);
        acc[4] += blo(raw.z); acc[5] += bhi(raw.z);
        acc[6] += blo(raw.w); acc[7] += bhi(raw.w);
    }
    uint4 o;
    o.x = pack2(acc[0] * inv, acc[1] * inv);
    o.y = pack2(acc[2] * inv, acc[3] * inv);
    o.z = pack2(acc[4] * inv, acc[5] * inv);
    o.w = pack2(acc[6] * inv, acc[7] * inv);
    *(uint4*)(att + flat) = o;
}

// ---------------------------------------------------------------------------
// Kernel 3: output projection via MFMA + fused BN partial sums. y bf16.
// ---------------------------------------------------------------------------
__global__ __launch_bounds__(256, 1) void outm_kernel(
    const u16* __restrict__ Wb, const u16* __restrict__ att,
    u16* __restrict__ y, float* __restrict__ stats) {
    const int n = blockIdx.z;
    const int o0 = blockIdx.y * 64;
    const int l0 = blockIdx.x * 128;
    const int tid = threadIdx.x;
    const int w = tid >> 6, lane = tid & 63;
    const int lhi = lane >> 4, llo = lane & 15;

    const u16* an = att + (size_t)n * LL * CH;
    const u16* Wm = Wb + 3 * 65536;

    bf16x8 af[8];
    const u16* abase = Wm + (size_t)(o0 + w * 16 + llo) * CH + lhi * 8;
#pragma unroll
    for (int ks = 0; ks < 8; ++ks) af[ks] = *(const bf16x8*)(abase + ks * 32);

    f32x4 acc[8];
#pragma unroll
    for (int t = 0; t < 8; ++t) acc[t] = (f32x4){0.f, 0.f, 0.f, 0.f};

#pragma unroll
    for (int ks = 0; ks < 8; ++ks) {
#pragma unroll
        for (int ct = 0; ct < 8; ++ct) {
            bf16x8 bf = *(const bf16x8*)(an + (size_t)(l0 + ct * 16 + llo) * CH +
                                         ks * 32 + lhi * 8);
            acc[ct] = __builtin_amdgcn_mfma_f32_16x16x32_bf16(af[ks], bf, acc[ct], 0, 0, 0);
        }
    }

    u16* yn = y + (size_t)n * CH * LL;
#pragma unroll
    for (int r = 0; r < 4; ++r) {
        const int orow = o0 + w * 16 + lhi * 4 + r;
        float ts = 0.0f, tq = 0.0f;
#pragma unroll
        for (int ct = 0; ct < 8; ++ct) {
            float vv = acc[ct][r];
            yn[(size_t)orow * LL + l0 + ct * 16 + llo] = f2b(vv);
            ts += vv;
            tq += vv * vv;
        }
        ts += __shfl_xor(ts, 1); tq += __shfl_xor(tq, 1);
        ts += __shfl_xor(ts, 2); tq += __shfl_xor(tq, 2);
        ts += __shfl_xor(ts, 4); tq += __shfl_xor(tq, 4);
        ts += __shfl_xor(ts, 8); tq += __shfl_xor(tq, 8);
        if (llo == 0) {
            atomicAdd(&stats[orow], ts);
            atomicAdd(&stats[256 + orow], tq);
        }
    }
}

// ---------------------------------------------------------------------------
// Kernel 4: BN apply (batch stats, biased var) + residual. y read as bf16.
// ---------------------------------------------------------------------------
__global__ __launch_bounds__(256) void bn_kernel(
    const float* __restrict__ x, const u16* __restrict__ y,
    const float* __restrict__ stats, const float* __restrict__ gamma,
    const float* __restrict__ beta, float* __restrict__ out) {
    const int idx = blockIdx.x * 256 + threadIdx.x;  // per 4 elems
    const int base = idx * 4;
    const int c = (base >> 12) & 255;  // (base / L) % C
    const float cnt = 1.0f / 16384.0f; // N*L
    float mean = stats[c] * cnt;
    float var = stats[256 + c] * cnt - mean * mean;
    float rstd = rsqrtf(var + 1e-4f);
    float g = gamma[c] * rstd;
    float b = beta[c];
    uint2 yv = ((const uint2*)y)[idx];
    float4 xv = ((const float4*)x)[idx];
    float4 o;
    o.x = xv.x + (blo(yv.x) - mean) * g + b;
    o.y = xv.y + (bhi(yv.x) - mean) * g + b;
    o.z = xv.z + (blo(yv.y) - mean) * g + b;
    o.w = xv.w + (bhi(yv.y) - mean) * g + b;
    ((float4*)out)[idx] = o;
}

// ---------------------------------------------------------------------------
extern "C" void kernel_launch(void* const* d_in, const int* in_sizes, int n_in,
                              void* d_out, int out_size, void* d_ws, size_t ws_size,
                              hipStream_t stream) {
    const float* x = (const float*)d_in[0];
    const float* Wq = (const float*)d_in[1];
    const float* Wk = (const float*)d_in[2];
    const float* Wv = (const float*)d_in[3];
    const float* Wo = (const float*)d_in[4];
    const float* gamma = (const float*)d_in[5];
    const float* beta = (const float*)d_in[6];
    float* out = (float*)d_out;

    const size_t elems = (size_t)NB * LL * CH;  // 4,194,304

    // pick largest split count whose workspace fits
    int S = 1;
    for (int cand = 8; cand >= 2; cand >>= 1) {
        size_t need = elems * 5 + elems * 2 * (size_t)cand +
                      (size_t)cand * NB * LL * 4 + 524288 + 8192;
        if (ws_size >= need) { S = cand; break; }
    }
    const int iters = 128 / S;

    char* wsb = (char*)d_ws;
    u16* q = (u16*)wsb;                             // 8.39 MB (bf16)
    u16* k = q + elems;                             // 8.39 MB (bf16)
    u8* v8 = (u8*)(k + elems);                      // 4.19 MB (fp8)
    u16* Op = (u16*)(v8 + elems);                   // S * 8.39 MB (bf16)
    u16* xT = Op;                                   // overlay: dead before fattn
    float* l_s = (float*)(Op + (size_t)S * elems);  // S * 64 KB
    u16* Wb = (u16*)(l_s + (size_t)S * NB * LL);    // 512 KB
    float* stats = (float*)(Wb + 4 * 65536);        // 2 KB
    u16* att = q;   // overlay q (dead after fattn)
    u16* y = k;     // overlay k (dead after merge)

    castw_kernel<<<dim3(64, 4), 256, 0, stream>>>(Wq, Wk, Wv, Wo, Wb, stats);
    tcast_kernel<<<dim3(LL / 64, CH / 64, NB), 256, 0, stream>>>(x, xT);
    projqk_kernel<<<dim3(LL / 64, 4, NB), 256, 0, stream>>>(xT, Wb, q, k);
    projv_kernel<<<dim3(LL / 128, CH / 64, NB), 256, 0, stream>>>(xT, Wb, v8);
    fattn_kernel<<<dim3(LL / 64, NB, S), 256, 0, stream>>>(q, k, v8, Op, l_s, iters);
    merge_kernel<<<(int)(elems / 8 / 256), 256, 0, stream>>>(Op, l_s, att, S);
    outm_kernel<<<dim3(LL / 128, CH / 64, NB), 256, 0, stream>>>(Wb, att, y, stats);
    bn_kernel<<<(NB * CH * LL / 4) / 256, 256, 0, stream>>>(x, y, stats, gamma, beta, out);
}

// Round 11
// 301.125 us; speedup vs baseline: 2.4971x; 1.0502x over previous
//
#include <hip/hip_runtime.h>
#include <cstdint>
#include <cstddef>

// Problem constants: N=4, C=D=256, H=W=64, L=4096
#define NB 4
#define CH 256
#define LL 4096

typedef unsigned short u16;
typedef unsigned int u32;
typedef unsigned char u8;
typedef __attribute__((ext_vector_type(8))) short bf16x8;
typedef __attribute__((ext_vector_type(4))) float f32x4;

#define GPTR(p) ((const __attribute__((address_space(1))) u32*)(p))
#define LPTR(p) ((__attribute__((address_space(3))) u32*)(p))

__device__ __forceinline__ float blo(u32 x) { return __uint_as_float(x << 16); }
__device__ __forceinline__ float bhi(u32 x) { return __uint_as_float(x & 0xffff0000u); }
__device__ __forceinline__ float b2f(u16 h) { return __uint_as_float(((u32)h) << 16); }
__device__ __forceinline__ u16 f2b(float f) {
    u32 u = __float_as_uint(f);
    u32 r = (u + 0x7fffu + ((u >> 16) & 1u)) >> 16;  // RNE
    return (u16)r;
}
__device__ __forceinline__ u32 pack2(float a, float b) {
    return (u32)f2b(a) | ((u32)f2b(b) << 16);
}

// ---------------------------------------------------------------------------
// Kernel 0b: cast weights to bf16 (Wb[mat][d][c]) + zero BN stats.
// ---------------------------------------------------------------------------
__global__ __launch_bounds__(256) void castw_kernel(
    const float* __restrict__ Wq, const float* __restrict__ Wk,
    const float* __restrict__ Wv, const float* __restrict__ Wo,
    u16* __restrict__ Wb, float* __restrict__ stats) {
    const int i = blockIdx.x * 256 + threadIdx.x;
    const int m = blockIdx.y;
    if (m == 0 && blockIdx.x < 2) stats[i] = 0.0f;
    const float* src = (m == 0) ? Wq : (m == 1) ? Wk : (m == 2) ? Wv : Wo;
    float4 v = ((const float4*)src)[i];
    uint2 o;
    o.x = pack2(v.x, v.y);
    o.y = pack2(v.z, v.w);
    ((uint2*)(Wb + m * 65536))[i] = o;
}

// ---------------------------------------------------------------------------
// Kernel 0c: transpose-cast x[n][c][l] f32 -> xT[n][l][c] bf16 (64x64 tiles).
// ---------------------------------------------------------------------------
__global__ __launch_bounds__(256) void tcast_kernel(
    const float* __restrict__ x, u16* __restrict__ xT) {
    const int n = blockIdx.z;
    const int c0 = blockIdx.y * 64, l0 = blockIdx.x * 64;
    __shared__ u16 t[64][72];
    const float* xs = x + (size_t)n * CH * LL;
    const int tid = threadIdx.x;
    const int lq = (tid & 15) * 4, cc = tid >> 4;
#pragma unroll
    for (int p = 0; p < 4; ++p) {
        int c = cc + p * 16;
        float4 v = *(const float4*)&xs[(size_t)(c0 + c) * LL + l0 + lq];
        t[lq + 0][c] = f2b(v.x);
        t[lq + 1][c] = f2b(v.y);
        t[lq + 2][c] = f2b(v.z);
        t[lq + 3][c] = f2b(v.w);
    }
    __syncthreads();
    u16* xo = xT + (size_t)n * LL * CH;
    const int l = tid >> 2, c8 = (tid & 3) * 16;
#pragma unroll
    for (int h = 0; h < 2; ++h) {
        uint4 vv = *(uint4*)&t[l][c8 + h * 8];
        *(uint4*)&xo[(size_t)(l0 + l) * CH + c0 + c8 + h * 8] = vv;
    }
}

// ---------------------------------------------------------------------------
// Kernel 1a: q/k projections via bf16 MFMA, output bf16. (fp8 q/k is the
// correlated-error path: R9 absmax 0.22 -- must stay bf16.)
// ---------------------------------------------------------------------------
__global__ __launch_bounds__(256, 1) void projqk_kernel(
    const u16* __restrict__ xT, const u16* __restrict__ Wb,
    u16* __restrict__ q, u16* __restrict__ k) {
    const int n = blockIdx.z;
    const int dhalf = blockIdx.y & 1, mat = blockIdx.y >> 1;
    const int l0 = blockIdx.x * 64;
    const int d0 = dhalf * 128;
    const int tid = threadIdx.x;
    const int w = tid >> 6, lane = tid & 63;
    const int lhi = lane >> 4, llo = lane & 15;

    const u16* xn = xT + (size_t)n * LL * CH;
    const u16* Wm = Wb + mat * 65536;

    bf16x8 af[8];
    const u16* abase = xn + (size_t)(l0 + w * 16 + llo) * CH + lhi * 8;
#pragma unroll
    for (int ks = 0; ks < 8; ++ks) af[ks] = *(const bf16x8*)(abase + ks * 32);

    f32x4 acc[8];
#pragma unroll
    for (int t = 0; t < 8; ++t) acc[t] = (f32x4){0.f, 0.f, 0.f, 0.f};

#pragma unroll
    for (int ks = 0; ks < 8; ++ks) {
#pragma unroll
        for (int ct = 0; ct < 8; ++ct) {
            bf16x8 bf = *(const bf16x8*)(Wm + (size_t)(d0 + ct * 16 + llo) * CH +
                                         ks * 32 + lhi * 8);
            acc[ct] = __builtin_amdgcn_mfma_f32_16x16x32_bf16(af[ks], bf, acc[ct], 0, 0, 0);
        }
    }

    u16* o = (mat ? k : q) + (size_t)n * LL * CH;
#pragma unroll
    for (int r = 0; r < 4; ++r) {
        int lr = l0 + w * 16 + lhi * 4 + r;
#pragma unroll
        for (int ct = 0; ct < 8; ++ct)
            o[(size_t)lr * CH + d0 + ct * 16 + llo] = f2b(acc[ct][r]);
    }
}

// ---------------------------------------------------------------------------
// Kernel 1b: v projection -> vT[n][d][l] bf16. (fp8 P/V reverted: R10 gave
// absmax 0.125 of 0.144 with ZERO speedup -- fattn is latency-bound, not
// LDS-throughput-bound.) A = Wv, B = xT.
// ---------------------------------------------------------------------------
__global__ __launch_bounds__(256, 1) void projv_kernel(
    const u16* __restrict__ xT, const u16* __restrict__ Wb,
    u16* __restrict__ vT) {
    const int n = blockIdx.z;
    const int d0 = blockIdx.y * 64;
    const int l0 = blockIdx.x * 128;
    const int tid = threadIdx.x;
    const int w = tid >> 6, lane = tid & 63;
    const int lhi = lane >> 4, llo = lane & 15;

    const u16* xn = xT + (size_t)n * LL * CH;
    const u16* Wm = Wb + 2 * 65536;

    bf16x8 af[8];
    const u16* abase = Wm + (size_t)(d0 + w * 16 + llo) * CH + lhi * 8;
#pragma unroll
    for (int ks = 0; ks < 8; ++ks) af[ks] = *(const bf16x8*)(abase + ks * 32);

    f32x4 acc[8];
#pragma unroll
    for (int t = 0; t < 8; ++t) acc[t] = (f32x4){0.f, 0.f, 0.f, 0.f};

#pragma unroll
    for (int ks = 0; ks < 8; ++ks) {
#pragma unroll
        for (int ct = 0; ct < 8; ++ct) {
            bf16x8 bf = *(const bf16x8*)(xn + (size_t)(l0 + ct * 16 + llo) * CH +
                                         ks * 32 + lhi * 8);
            acc[ct] = __builtin_amdgcn_mfma_f32_16x16x32_bf16(af[ks], bf, acc[ct], 0, 0, 0);
        }
    }

    u16* o = vT + (size_t)n * CH * LL;
#pragma unroll
    for (int r = 0; r < 4; ++r) {
        int dr = d0 + w * 16 + lhi * 4 + r;
#pragma unroll
        for (int ct = 0; ct < 8; ++ct)
            o[(size_t)dr * LL + l0 + ct * 16 + llo] = f2b(acc[ct][r]);
    }
}

// ---------------------------------------------------------------------------
// Kernel 2: bf16 flash attention, key-split, DOUBLE-BUFFERED K/V tiles.
// One barrier per iter: sync (drains tile i, issued last iter) -> issue tile
// i+1 into the other buffer -> compute tile i. Loads fly during a full
// compute iteration, hiding the vmcnt(0) drain that R7-R10 exposed each iter.
// All-bf16 numerics (R8-verified); P round-trip wave-private (no barrier).
// LDS 71168 B (gfx950 allows up to 160K/WG): K[2][32][256] | V[2][256][32]
// (chunk-XOR swizzles from R7) | P[64][44] @65536. 2 blocks/CU.
// ---------------------------------------------------------------------------
#define PSTRIDE 44
#define P_OFF 65536

__global__ __launch_bounds__(256, 1) void fattn_kernel(
    const u16* __restrict__ q, const u16* __restrict__ k,
    const u16* __restrict__ vT, u16* __restrict__ Op, float* __restrict__ l_s,
    int iters) {
    const int n = blockIdx.y;
    const int s_id = blockIdx.z;
    const int l0 = blockIdx.x * 64;
    const int m_base = s_id * iters * 32;
    const int tid = threadIdx.x;
    const int w = tid >> 6;
    const int lane = tid & 63;
    const int lhi = lane >> 4, llo = lane & 15;

    __shared__ __align__(16) char smem[71168];
    // K buffers @ 0 / 16384 ; V buffers @ 32768 / 49152 ; P @ 65536

    // ---- Q fragments (A-layout, bf16) direct from global ----
    bf16x8 qf[8];
    {
        const u16* base = q + (size_t)(n * LL + l0 + w * 16 + llo) * CH + lhi * 8;
#pragma unroll
        for (int ks = 0; ks < 8; ++ks) qf[ks] = *(const bf16x8*)(base + ks * 32);
    }

    const u16* kg = k + (size_t)n * LL * CH;
    const u16* vg = vT + (size_t)n * CH * LL;

    // iter-invariant swizzled offsets (u16 elems); slot s = i*256 + tid
    int okK[4], okV[4];
#pragma unroll
    for (int i = 0; i < 4; ++i) {
        int s = i * 256 + tid;
        int rK = s >> 5;
        int cK = (s & 31) ^ rK;
        okK[i] = rK * CH + cK * 8;
        int dV = s >> 2;
        int cV = (s & 3) ^ ((dV & 3) ^ ((dV >> 2) & 3));
        okV[i] = dV * LL + cV * 8;
    }

    f32x4 oacc[16];
#pragma unroll
    for (int t = 0; t < 16; ++t) oacc[t] = (f32x4){0.f, 0.f, 0.f, 0.f};
    float lrun[4] = {0.f, 0.f, 0.f, 0.f};

    const float C1 = 0.09016844005556021f;  // (1/16) * log2(e)
    const int posV = (lhi ^ ((llo & 3) ^ (llo >> 2))) * 8;

    // ---- prologue: issue tile 0 into buffer 0 ----
    {
        const u16* kg2 = kg + (size_t)m_base * CH;
        const u16* vg2 = vg + m_base;
#pragma unroll
        for (int i = 0; i < 4; ++i) {
            __builtin_amdgcn_global_load_lds(GPTR(kg2 + okK[i]),
                                             LPTR(smem + i * 4096 + w * 1024), 16, 0, 0);
            __builtin_amdgcn_global_load_lds(GPTR(vg2 + okV[i]),
                                             LPTR(smem + 32768 + i * 4096 + w * 1024),
                                             16, 0, 0);
        }
    }

    for (int it = 0; it < iters; ++it) {
        __syncthreads();  // drains tile-it loads; prev compute done with other buf
        if (it + 1 < iters) {
            const int m1 = m_base + (it + 1) * 32;
            const u16* kg2 = kg + (size_t)m1 * CH;
            const u16* vg2 = vg + m1;
            char* Kb = smem + ((it + 1) & 1) * 16384;
            char* Vb = smem + 32768 + ((it + 1) & 1) * 16384;
#pragma unroll
            for (int i = 0; i < 4; ++i) {
                __builtin_amdgcn_global_load_lds(GPTR(kg2 + okK[i]),
                                                 LPTR(Kb + i * 4096 + w * 1024), 16, 0, 0);
                __builtin_amdgcn_global_load_lds(GPTR(vg2 + okV[i]),
                                                 LPTR(Vb + i * 4096 + w * 1024), 16, 0, 0);
            }
        }
        const u16* Kl = (const u16*)(smem + (it & 1) * 16384);
        const u16* Vl = (const u16*)(smem + 32768 + (it & 1) * 16384);
        u16* Pl = (u16*)(smem + P_OFF);

        // ---- S = Q·K^T : 2 col-tiles x 8 k-steps ----
        f32x4 s0 = (f32x4){0.f, 0.f, 0.f, 0.f};
        f32x4 s1 = (f32x4){0.f, 0.f, 0.f, 0.f};
#pragma unroll
        for (int ks = 0; ks < 8; ++ks) {
            const int cq = ks * 4 + lhi;
            bf16x8 b0 = *(const bf16x8*)(Kl + llo * 256 + (cq ^ llo) * 8);
            bf16x8 b1 = *(const bf16x8*)(Kl + (llo + 16) * 256 + (cq ^ (llo + 16)) * 8);
            s0 = __builtin_amdgcn_mfma_f32_16x16x32_bf16(qf[ks], b0, s0, 0, 0, 0);
            s1 = __builtin_amdgcn_mfma_f32_16x16x32_bf16(qf[ks], b1, s1, 0, 0, 0);
        }

        // ---- p = exp2(s * C1), write bf16 P; lrun += p ----
        u16* pw = Pl + (w * 16) * PSTRIDE;
#pragma unroll
        for (int r = 0; r < 4; ++r) {
            float p0 = __builtin_amdgcn_exp2f(s0[r] * C1);
            float p1 = __builtin_amdgcn_exp2f(s1[r] * C1);
            int lrow = lhi * 4 + r;
            pw[lrow * PSTRIDE + llo] = f2b(p0);
            pw[lrow * PSTRIDE + 16 + llo] = f2b(p1);
            lrun[r] += p0 + p1;
        }

        // ---- PV (wave-private P rows; no barrier) ----
        bf16x8 pf = *(const bf16x8*)(Pl + (w * 16 + llo) * PSTRIDE + lhi * 8);
#pragma unroll
        for (int ct = 0; ct < 16; ++ct) {
            bf16x8 vf = *(const bf16x8*)(Vl + (ct * 16 + llo) * 32 + posV);
            oacc[ct] = __builtin_amdgcn_mfma_f32_16x16x32_bf16(pf, vf, oacc[ct], 0, 0, 0);
        }
    }

    // ---- epilogue: store un-normalized partial O (bf16) + l (fp32) ----
    u16* ap = Op + (size_t)((s_id * NB + n) * (size_t)LL + l0 + w * 16) * CH;
    float* lp = l_s + (size_t)s_id * NB * LL + (size_t)n * LL + l0 + w * 16;
#pragma unroll
    for (int r = 0; r < 4; ++r) {
        float t = lrun[r];
        t += __shfl_xor(t, 1);
        t += __shfl_xor(t, 2);
        t += __shfl_xor(t, 4);
        t += __shfl_xor(t, 8);
        int lrow = lhi * 4 + r;
#pragma unroll
        for (int ct = 0; ct < 16; ++ct) {
            ap[(size_t)lrow * CH + ct * 16 + llo] = f2b(oacc[ct][r]);
        }
        if (llo == 0) lp[lrow] = t;
    }
}

// ---------------------------------------------------------------------------
// Kernel 2c: merge splits: att[i] = (sum_s Op[s][i]) / (sum_s l_s[s][row])
// ---------------------------------------------------------------------------
__global__ __launch_bounds__(256) void merge_kernel(
    const u16* __restrict__ Op, const float* __restrict__ l_s,
    u16* __restrict__ att, int S) {
    const size_t t8 = (size_t)blockIdx.x * 256 + threadIdx.x;
    const size_t flat = t8 * 8;
    const size_t row = flat >> 8;
    float lsum = 0.0f;
    for (int s = 0; s < S; ++s) lsum += l_s[(size_t)s * NB * LL + row];
    const float inv = 1.0f / lsum;
    float acc[8];
#pragma unroll
    for (int j = 0; j < 8; ++j) acc[j] = 0.0f;
    for (int s = 0; s < S; ++s) {
        uint4 raw = *(const uint4*)(Op + (size_t)s * NB * LL * CH + flat);
        acc[0] += blo(raw.x); acc[1] += bhi(raw.x);
        acc[2] += blo(raw.y); acc[3] += bhi(raw.y);
        acc[4] += blo(raw.z); acc[5] += bhi(raw.z);
        acc[6] += blo(raw.w); acc[7] += bhi(raw.w);
    }
    uint4 o;
    o.x = pack2(acc[0] * inv, acc[1] * inv);
    o.y = pack2(acc[2] * inv, acc[3] * inv);
    o.z = pack2(acc[4] * inv, acc[5] * inv);
    o.w = pack2(acc[6] * inv, acc[7] * inv);
    *(uint4*)(att + flat) = o;
}

// ---------------------------------------------------------------------------
// Kernel 3: output projection via MFMA + fused BN partial sums. y bf16.
// ---------------------------------------------------------------------------
__global__ __launch_bounds__(256, 1) void outm_kernel(
    const u16* __restrict__ Wb, const u16* __restrict__ att,
    u16* __restrict__ y, float* __restrict__ stats) {
    const int n = blockIdx.z;
    const int o0 = blockIdx.y * 64;
    const int l0 = blockIdx.x * 128;
    const int tid = threadIdx.x;
    const int w = tid >> 6, lane = tid & 63;
    const int lhi = lane >> 4, llo = lane & 15;

    const u16* an = att + (size_t)n * LL * CH;
    const u16* Wm = Wb + 3 * 65536;

    bf16x8 af[8];
    const u16* abase = Wm + (size_t)(o0 + w * 16 + llo) * CH + lhi * 8;
#pragma unroll
    for (int ks = 0; ks < 8; ++ks) af[ks] = *(const bf16x8*)(abase + ks * 32);

    f32x4 acc[8];
#pragma unroll
    for (int t = 0; t < 8; ++t) acc[t] = (f32x4){0.f, 0.f, 0.f, 0.f};

#pragma unroll
    for (int ks = 0; ks < 8; ++ks) {
#pragma unroll
        for (int ct = 0; ct < 8; ++ct) {
            bf16x8 bf = *(const bf16x8*)(an + (size_t)(l0 + ct * 16 + llo) * CH +
                                         ks * 32 + lhi * 8);
            acc[ct] = __builtin_amdgcn_mfma_f32_16x16x32_bf16(af[ks], bf, acc[ct], 0, 0, 0);
        }
    }

    u16* yn = y + (size_t)n * CH * LL;
#pragma unroll
    for (int r = 0; r < 4; ++r) {
        const int orow = o0 + w * 16 + lhi * 4 + r;
        float ts = 0.0f, tq = 0.0f;
#pragma unroll
        for (int ct = 0; ct < 8; ++ct) {
            float vv = acc[ct][r];
            yn[(size_t)orow * LL + l0 + ct * 16 + llo] = f2b(vv);
            ts += vv;
            tq += vv * vv;
        }
        ts += __shfl_xor(ts, 1); tq += __shfl_xor(tq, 1);
        ts += __shfl_xor(ts, 2); tq += __shfl_xor(tq, 2);
        ts += __shfl_xor(ts, 4); tq += __shfl_xor(tq, 4);
        ts += __shfl_xor(ts, 8); tq += __shfl_xor(tq, 8);
        if (llo == 0) {
            atomicAdd(&stats[orow], ts);
            atomicAdd(&stats[256 + orow], tq);
        }
    }
}

// ---------------------------------------------------------------------------
// Kernel 4: BN apply (batch stats, biased var) + residual. y read as bf16.
// ---------------------------------------------------------------------------
__global__ __launch_bounds__(256) void bn_kernel(
    const float* __restrict__ x, const u16* __restrict__ y,
    const float* __restrict__ stats, const float* __restrict__ gamma,
    const float* __restrict__ beta, float* __restrict__ out) {
    const int idx = blockIdx.x * 256 + threadIdx.x;  // per 4 elems
    const int base = idx * 4;
    const int c = (base >> 12) & 255;  // (base / L) % C
    const float cnt = 1.0f / 16384.0f; // N*L
    float mean = stats[c] * cnt;
    float var = stats[256 + c] * cnt - mean * mean;
    float rstd = rsqrtf(var + 1e-4f);
    float g = gamma[c] * rstd;
    float b = beta[c];
    uint2 yv = ((const uint2*)y)[idx];
    float4 xv = ((const float4*)x)[idx];
    float4 o;
    o.x = xv.x + (blo(yv.x) - mean) * g + b;
    o.y = xv.y + (bhi(yv.x) - mean) * g + b;
    o.z = xv.z + (blo(yv.y) - mean) * g + b;
    o.w = xv.w + (bhi(yv.y) - mean) * g + b;
    ((float4*)out)[idx] = o;
}

// ---------------------------------------------------------------------------
extern "C" void kernel_launch(void* const* d_in, const int* in_sizes, int n_in,
                              void* d_out, int out_size, void* d_ws, size_t ws_size,
                              hipStream_t stream) {
    const float* x = (const float*)d_in[0];
    const float* Wq = (const float*)d_in[1];
    const float* Wk = (const float*)d_in[2];
    const float* Wv = (const float*)d_in[3];
    const float* Wo = (const float*)d_in[4];
    const float* gamma = (const float*)d_in[5];
    const float* beta = (const float*)d_in[6];
    float* out = (float*)d_out;

    const size_t elems = (size_t)NB * LL * CH;  // 4,194,304

    // pick largest split count whose workspace fits (S=4 needs ~59.4 MB)
    int S = 1;
    for (int cand = 4; cand >= 2; cand >>= 1) {
        size_t need = elems * 2 * (size_t)(3 + cand) +
                      (size_t)cand * NB * LL * 4 + 524288 + 8192;
        if (ws_size >= need) { S = cand; break; }
    }
    const int iters = 128 / S;

    char* wsb = (char*)d_ws;
    u16* q = (u16*)wsb;                             // 8.39 MB (bf16)
    u16* k = q + elems;                             // 8.39 MB (bf16)
    u16* vT = k + elems;                            // 8.39 MB (bf16)
    u16* Op = vT + elems;                           // S * 8.39 MB (bf16)
    u16* xT = Op;                                   // overlay: dead before fattn
    float* l_s = (float*)(Op + (size_t)S * elems);  // S * 64 KB
    u16* Wb = (u16*)(l_s + (size_t)S * NB * LL);    // 512 KB
    float* stats = (float*)(Wb + 4 * 65536);        // 2 KB
    u16* att = q;   // overlay q (dead after fattn)
    u16* y = k;     // overlay k (dead after merge)

    castw_kernel<<<dim3(64, 4), 256, 0, stream>>>(Wq, Wk, Wv, Wo, Wb, stats);
    tcast_kernel<<<dim3(LL / 64, CH / 64, NB), 256, 0, stream>>>(x, xT);
    projqk_kernel<<<dim3(LL / 64, 4, NB), 256, 0, stream>>>(xT, Wb, q, k);
    projv_kernel<<<dim3(LL / 128, CH / 64, NB), 256, 0, stream>>>(xT, Wb, vT);
    fattn_kernel<<<dim3(LL / 64, NB, S), 256, 0, stream>>>(q, k, vT, Op, l_s, iters);
    merge_kernel<<<(int)(elems / 8 / 256), 256, 0, stream>>>(Op, l_s, att, S);
    outm_kernel<<<dim3(LL / 128, CH / 64, NB), 256, 0, stream>>>(Wb, att, y, stats);
    bn_kernel<<<(NB * CH * LL / 4) / 256, 256, 0, stream>>>(x, y, stats, gamma, beta, out);
}